// Round 2
// baseline (2395.366 us; speedup 1.0000x reference)
//
#include <hip/hip_runtime.h>

// LSH attention, B=4, T=4096, D=512, H=8 hashes, 64 buckets/hash, bucket size 64.
// Round 2: all-fp32 bucket path with sequential-over-K fma accumulation to
// mirror the fp32 reference's (BLAS/Eigen-style) rounding; fp64 path removed —
// it was *less* correlated with the fp32 golden ref than another fp32 impl is.

// ---------------- GEMM fp32: C[M,N] = A[M,K] @ W[K,N] + bias[N] ----------------
// 128x128 block tile, 256 threads, 8x8 micro-tile, BK=16. Sequential fma over K.
__global__ __launch_bounds__(256) void gemm_bias_f32(
    const float* __restrict__ A, const float* __restrict__ W,
    const float* __restrict__ bias, float* __restrict__ C,
    int M, int N, int K)
{
  __shared__ float As[16][136];
  __shared__ float Bs[16][136];
  const int bm = blockIdx.x * 128, bn = blockIdx.y * 128;
  const int tid = threadIdx.x, tx = tid & 15, ty = tid >> 4;
  float acc[8][8] = {};
  for (int k0 = 0; k0 < K; k0 += 16) {
    {
      const int r = tid >> 1, q = tid & 1;
      const float* src = A + (size_t)(bm + r) * K + k0 + q * 8;
      float4 v0 = *(const float4*)src;
      float4 v1 = *(const float4*)(src + 4);
      const int kk = q * 8;
      As[kk+0][r]=v0.x; As[kk+1][r]=v0.y; As[kk+2][r]=v0.z; As[kk+3][r]=v0.w;
      As[kk+4][r]=v1.x; As[kk+5][r]=v1.y; As[kk+6][r]=v1.z; As[kk+7][r]=v1.w;
    }
    {
      const int kr = tid >> 4, c4 = (tid & 15) * 4;
      const float* src = W + (size_t)(k0 + kr) * N + bn;
      *(float4*)&Bs[kr][c4]      = *(const float4*)(src + c4);
      *(float4*)&Bs[kr][c4 + 64] = *(const float4*)(src + c4 + 64);
    }
    __syncthreads();
    #pragma unroll
    for (int k = 0; k < 16; ++k) {
      float a[8], bb[8];
      *(float4*)&a[0]  = *(const float4*)&As[k][ty*8];
      *(float4*)&a[4]  = *(const float4*)&As[k][ty*8+4];
      *(float4*)&bb[0] = *(const float4*)&Bs[k][tx*8];
      *(float4*)&bb[4] = *(const float4*)&Bs[k][tx*8+4];
      #pragma unroll
      for (int i = 0; i < 8; ++i)
        #pragma unroll
        for (int j = 0; j < 8; ++j)
          acc[i][j] = fmaf(a[i], bb[j], acc[i][j]);
    }
    __syncthreads();
  }
  #pragma unroll
  for (int i = 0; i < 8; ++i) {
    const int row = bm + ty*8 + i;
    float* dst = C + (size_t)row * N + bn + tx*8;
    const float* bp = bias + bn + tx*8;
    float o[8];
    #pragma unroll
    for (int j = 0; j < 8; ++j) o[j] = acc[i][j] + bp[j];
    *(float4*)dst       = *(float4*)&o[0];
    *(float4*)(dst + 4) = *(float4*)&o[4];
  }
}

// -------- rot[M=16384, 256] = QK[M,512] @ R[512,256], fp32 sequential-K fma --------
// Two-step like the reference: consumes the already-fp32-rounded qk buffer.
__global__ __launch_bounds__(256) void rot_gemm_f32(
    const float* __restrict__ QK, const float* __restrict__ R,
    float* __restrict__ rot)
{
  __shared__ float As[16][68];
  __shared__ float Bs[16][68];
  const int bm = blockIdx.x * 64, bn = blockIdx.y * 64;
  const int tid = threadIdx.x, tx = tid & 15, ty = tid >> 4;
  float acc[4][4] = {};
  for (int k0 = 0; k0 < 512; k0 += 16) {
    {
      const int r = tid >> 2, q = tid & 3;
      float4 av = *(const float4*)(QK + (size_t)(bm + r) * 512 + k0 + q * 4);
      As[q*4+0][r]=av.x; As[q*4+1][r]=av.y; As[q*4+2][r]=av.z; As[q*4+3][r]=av.w;
    }
    {
      const int kr = tid >> 4, n4 = (tid & 15) * 4;
      *(float4*)&Bs[kr][n4] = *(const float4*)(R + (size_t)(k0 + kr) * 256 + bn + n4);
    }
    __syncthreads();
    #pragma unroll
    for (int k = 0; k < 16; ++k) {
      float a[4], bb[4];
      #pragma unroll
      for (int i = 0; i < 4; ++i) a[i] = As[k][ty*4+i];
      #pragma unroll
      for (int j = 0; j < 4; ++j) bb[j] = Bs[k][tx*4+j];
      #pragma unroll
      for (int i = 0; i < 4; ++i)
        #pragma unroll
        for (int j = 0; j < 4; ++j)
          acc[i][j] = fmaf(a[i], bb[j], acc[i][j]);
    }
    __syncthreads();
  }
  #pragma unroll
  for (int i = 0; i < 4; ++i)
    #pragma unroll
    for (int j = 0; j < 4; ++j)
      rot[(size_t)(bm + ty*4 + i) * 256 + (bn + tx*4 + j)] = acc[i][j];
}

// -------- bucket = argmax over [rot, -rot] (64 candidates) per (token, hash) --------
// First-index-wins tie-break == jnp.argmax on the concat order.
__global__ __launch_bounds__(256) void argmax_kernel(
    const float* __restrict__ rot, int* __restrict__ buckets)
{
  const int tok = blockIdx.x;
  const int j = threadIdx.x;             // j = h*32 + i
  const float r = rot[(size_t)tok * 256 + j];
  float val = (r >= 0.f) ? r : -r;
  int   idx = (r >= 0.f) ? (j & 31) : (j & 31) + 32;
  #pragma unroll
  for (int off = 16; off; off >>= 1) {   // reduce within 32-lane hash group
    const float ov = __shfl_xor(val, off);
    const int   oi = __shfl_xor(idx, off);
    if (ov > val || (ov == val && oi < idx)) { val = ov; idx = oi; }
  }
  if ((j & 31) == 0) {
    const int h = j >> 5, b = tok >> 12, t = tok & 4095;
    buckets[((b << 3) + h) * 4096 + t] = idx;
  }
}

// -------- stable counting sort per (b,h): tokens by (bucket, t) --------
__global__ __launch_bounds__(256) void sort_kernel(
    const int* __restrict__ buckets, int* __restrict__ st)
{
  __shared__ int bk_lds[4096];
  __shared__ int cnt[4][64];
  __shared__ int startq[4][64];
  const int tid = threadIdx.x;
  const int base = blockIdx.x * 4096;     // blockIdx = b*8+h
  for (int t = tid; t < 4096; t += 256) bk_lds[t] = buckets[base + t];
  __syncthreads();
  const int wave = tid >> 6, lane = tid & 63;
  const int q0 = wave * 1024;
  int c = 0;
  for (int t = 0; t < 1024; ++t) c += (bk_lds[q0 + t] == lane);
  cnt[wave][lane] = c;
  __syncthreads();
  if (tid < 64) {
    const int c0 = cnt[0][tid], c1 = cnt[1][tid], c2 = cnt[2][tid], c3 = cnt[3][tid];
    const int tot = c0 + c1 + c2 + c3;
    int ex = tot;                          // inclusive scan over buckets
    #pragma unroll
    for (int off = 1; off < 64; off <<= 1) {
      const int n = __shfl_up(ex, off);
      if (lane >= off) ex += n;
    }
    const int bucket_start = ex - tot;     // exclusive
    startq[0][tid] = bucket_start;
    startq[1][tid] = bucket_start + c0;
    startq[2][tid] = bucket_start + c0 + c1;
    startq[3][tid] = bucket_start + c0 + c1 + c2;
  }
  __syncthreads();
  int cur = startq[wave][lane];
  for (int t = 0; t < 1024; ++t) {
    if (bk_lds[q0 + t] == lane) { st[base + cur] = q0 + t; cur++; }
  }
}

// -------- scale[token] = D^-0.5 / max(||qk_row||, 1e-12) --------
__global__ __launch_bounds__(256) void scale_kernel(
    const float* __restrict__ qk, float* __restrict__ scale)
{
  const int wave = threadIdx.x >> 6, lane = threadIdx.x & 63;
  const int tok = blockIdx.x * 4 + wave;
  const float4* row = (const float4*)(qk + (size_t)tok * 512);
  const float4 p0 = row[lane], p1 = row[lane + 64];
  float s = p0.x*p0.x + p0.y*p0.y + p0.z*p0.z + p0.w*p0.w
          + p1.x*p1.x + p1.y*p1.y + p1.z*p1.z + p1.w*p1.w;
  #pragma unroll
  for (int off = 32; off; off >>= 1) s += __shfl_down(s, off);
  if (lane == 0) {
    const float n = fmaxf(sqrtf(s), 1e-12f);
    scale[tok] = 0.044194173824159216f / n;   // 512^-0.5 / norm
  }
}

// -------- chunked attention: per chunk of 64 sorted tokens --------
// dots[i][j] = (bq_i . bq_j) * scale_j ; bo = dots @ bv ; atomicAdd into o_acc[token]
__global__ __launch_bounds__(256) void attn_kernel(
    const float* __restrict__ qk, const float* __restrict__ v,
    const float* __restrict__ scale, const int* __restrict__ st,
    float* __restrict__ o_acc)
{
  __shared__ float tile[64][132];
  __shared__ float dlds[64][68];
  __shared__ int   stt[64];
  __shared__ float scl[64];
  const int blk = blockIdx.x;
  const int b = blk >> 9, c = blk & 511;   // 512 chunks per batch
  const int tid = threadIdx.x, tx = tid & 15, ty = tid >> 4;
  if (tid < 64) {
    const int s = st[(size_t)b * 32768 + c * 64 + tid];
    stt[tid] = s;
    scl[tid] = scale[b * 4096 + s];
  }
  __syncthreads();
  const int r = tid >> 2, q = tid & 3;
  const size_t rowbase = ((size_t)b * 4096 + stt[r]) * 512;

  float S[4][4] = {};
  for (int dt = 0; dt < 4; ++dt) {
    const float* src = qk + rowbase + dt * 128;
    #pragma unroll
    for (int s8 = 0; s8 < 8; ++s8) {
      const int col = q * 4 + s8 * 16;
      *(float4*)&tile[r][col] = *(const float4*)(src + col);
    }
    __syncthreads();
    #pragma unroll 8
    for (int k = 0; k < 128; ++k) {
      const float a0=tile[ty*4+0][k], a1=tile[ty*4+1][k], a2=tile[ty*4+2][k], a3=tile[ty*4+3][k];
      const float b0=tile[tx*4+0][k], b1=tile[tx*4+1][k], b2=tile[tx*4+2][k], b3=tile[tx*4+3][k];
      S[0][0]=fmaf(a0,b0,S[0][0]); S[0][1]=fmaf(a0,b1,S[0][1]); S[0][2]=fmaf(a0,b2,S[0][2]); S[0][3]=fmaf(a0,b3,S[0][3]);
      S[1][0]=fmaf(a1,b0,S[1][0]); S[1][1]=fmaf(a1,b1,S[1][1]); S[1][2]=fmaf(a1,b2,S[1][2]); S[1][3]=fmaf(a1,b3,S[1][3]);
      S[2][0]=fmaf(a2,b0,S[2][0]); S[2][1]=fmaf(a2,b1,S[2][1]); S[2][2]=fmaf(a2,b2,S[2][2]); S[2][3]=fmaf(a2,b3,S[2][3]);
      S[3][0]=fmaf(a3,b0,S[3][0]); S[3][1]=fmaf(a3,b1,S[3][1]); S[3][2]=fmaf(a3,b2,S[3][2]); S[3][3]=fmaf(a3,b3,S[3][3]);
    }
    __syncthreads();
  }
  #pragma unroll
  for (int i = 0; i < 4; ++i)
    #pragma unroll
    for (int j = 0; j < 4; ++j)
      dlds[ty*4+i][tx*4+j] = S[i][j] * scl[tx*4+j];
  __syncthreads();

  for (int dt = 0; dt < 4; ++dt) {
    const float* src = v + rowbase + dt * 128;
    #pragma unroll
    for (int s8 = 0; s8 < 8; ++s8) {
      const int col = q * 4 + s8 * 16;
      *(float4*)&tile[r][col] = *(const float4*)(src + col);
    }
    __syncthreads();
    float o[4][8] = {};
    #pragma unroll 4
    for (int j = 0; j < 64; ++j) {
      const float a0=dlds[ty*4+0][j], a1=dlds[ty*4+1][j], a2=dlds[ty*4+2][j], a3=dlds[ty*4+3][j];
      float bb[8];
      *(float4*)&bb[0] = *(const float4*)&tile[j][tx*8];
      *(float4*)&bb[4] = *(const float4*)&tile[j][tx*8+4];
      #pragma unroll
      for (int d = 0; d < 8; ++d) {
        o[0][d]=fmaf(a0,bb[d],o[0][d]); o[1][d]=fmaf(a1,bb[d],o[1][d]);
        o[2][d]=fmaf(a2,bb[d],o[2][d]); o[3][d]=fmaf(a3,bb[d],o[3][d]);
      }
    }
    #pragma unroll
    for (int i = 0; i < 4; ++i) {
      float* dst = o_acc + ((size_t)b * 4096 + stt[ty*4+i]) * 512 + dt * 128 + tx * 8;
      #pragma unroll
      for (int d = 0; d < 8; ++d) atomicAdd(dst + d, o[i][d]);
    }
    __syncthreads();
  }
}

extern "C" void kernel_launch(void* const* d_in, const int* in_sizes, int n_in,
                              void* d_out, int out_size, void* d_ws, size_t ws_size,
                              hipStream_t stream) {
  const float* x         = (const float*)d_in[0];
  const float* rotations = (const float*)d_in[1];
  const float* w_qk      = (const float*)d_in[2];
  const float* b_qk      = (const float*)d_in[3];
  const float* w_v       = (const float*)d_in[4];
  const float* b_v       = (const float*)d_in[5];
  const float* w_out     = (const float*)d_in[6];
  const float* b_out     = (const float*)d_in[7];
  float* out = (float*)d_out;
  char* ws = (char*)d_ws;

  float*  qk      = (float*)(ws);                     // 33.55 MB
  float*  vbuf    = (float*)(ws + 33554432);          // 33.55 MB
  float*  o_acc   = (float*)(ws + 67108864);          // 33.55 MB
  float*  rot     = o_acc;                            // alias: rot (16.8MB) dead before o_acc lives
  float*  scale   = (float*)(ws + 100663296);         // 64 KB
  int*    buckets = (int*)(ws + 100728832);           // 512 KB
  int*    st      = (int*)(ws + 101253120);           // 512 KB

  const dim3 gemm_grid(128, 4), blk256(256);
  hipLaunchKernelGGL(gemm_bias_f32, gemm_grid, blk256, 0, stream, x, w_qk, b_qk, qk, 16384, 512, 512);
  hipLaunchKernelGGL(gemm_bias_f32, gemm_grid, blk256, 0, stream, x, w_v, b_v, vbuf, 16384, 512, 512);
  hipLaunchKernelGGL(rot_gemm_f32, dim3(256, 4), blk256, 0, stream, qk, rotations, rot);
  hipLaunchKernelGGL(argmax_kernel, dim3(16384), blk256, 0, stream, rot, buckets);
  hipLaunchKernelGGL(sort_kernel, dim3(32), blk256, 0, stream, buckets, st);
  hipLaunchKernelGGL(scale_kernel, dim3(4096), blk256, 0, stream, qk, scale);
  hipMemsetAsync(o_acc, 0, 33554432, stream);
  hipLaunchKernelGGL(attn_kernel, dim3(2048), blk256, 0, stream, qk, vbuf, scale, st, o_acc);
  hipLaunchKernelGGL(gemm_bias_f32, gemm_grid, blk256, 0, stream, o_acc, w_out, b_out, out, 16384, 512, 512);
}

// Round 3
// 883.442 us; speedup vs baseline: 2.7114x; 2.7114x over previous
//
#include <hip/hip_runtime.h>
#include <hip/hip_bf16.h>

// LSH attention, B=4, T=4096, D=512, H=8 hashes, 64 buckets/hash, bucket size 64.
// Round 3: atomic-free hash combination. Attention stores its (disjoint) sorted
// rows to a bf16 `so` buffer; a gather kernel sums the 8 hash rounds per token
// using the token->sorted-position map from the sort. LDS pad 132->133 kills the
// 8-way bank conflict on the B-operand read.

// ---------------- GEMM fp32: C[M,N] = A[M,K] @ W[K,N] + bias[N] ----------------
__global__ __launch_bounds__(256) void gemm_bias_f32(
    const float* __restrict__ A, const float* __restrict__ W,
    const float* __restrict__ bias, float* __restrict__ C,
    int M, int N, int K)
{
  __shared__ float As[16][136];
  __shared__ float Bs[16][136];
  const int bm = blockIdx.x * 128, bn = blockIdx.y * 128;
  const int tid = threadIdx.x, tx = tid & 15, ty = tid >> 4;
  float acc[8][8] = {};
  for (int k0 = 0; k0 < K; k0 += 16) {
    {
      const int r = tid >> 1, q = tid & 1;
      const float* src = A + (size_t)(bm + r) * K + k0 + q * 8;
      float4 v0 = *(const float4*)src;
      float4 v1 = *(const float4*)(src + 4);
      const int kk = q * 8;
      As[kk+0][r]=v0.x; As[kk+1][r]=v0.y; As[kk+2][r]=v0.z; As[kk+3][r]=v0.w;
      As[kk+4][r]=v1.x; As[kk+5][r]=v1.y; As[kk+6][r]=v1.z; As[kk+7][r]=v1.w;
    }
    {
      const int kr = tid >> 4, c4 = (tid & 15) * 4;
      const float* src = W + (size_t)(k0 + kr) * N + bn;
      *(float4*)&Bs[kr][c4]      = *(const float4*)(src + c4);
      *(float4*)&Bs[kr][c4 + 64] = *(const float4*)(src + c4 + 64);
    }
    __syncthreads();
    #pragma unroll
    for (int k = 0; k < 16; ++k) {
      float a[8], bb[8];
      *(float4*)&a[0]  = *(const float4*)&As[k][ty*8];
      *(float4*)&a[4]  = *(const float4*)&As[k][ty*8+4];
      *(float4*)&bb[0] = *(const float4*)&Bs[k][tx*8];
      *(float4*)&bb[4] = *(const float4*)&Bs[k][tx*8+4];
      #pragma unroll
      for (int i = 0; i < 8; ++i)
        #pragma unroll
        for (int j = 0; j < 8; ++j)
          acc[i][j] = fmaf(a[i], bb[j], acc[i][j]);
    }
    __syncthreads();
  }
  #pragma unroll
  for (int i = 0; i < 8; ++i) {
    const int row = bm + ty*8 + i;
    float* dst = C + (size_t)row * N + bn + tx*8;
    const float* bp = bias + bn + tx*8;
    float o[8];
    #pragma unroll
    for (int j = 0; j < 8; ++j) o[j] = acc[i][j] + bp[j];
    *(float4*)dst       = *(float4*)&o[0];
    *(float4*)(dst + 4) = *(float4*)&o[4];
  }
}

// -------- rot[M=16384, 256] = QK[M,512] @ R[512,256], fp32 sequential-K fma --------
__global__ __launch_bounds__(256) void rot_gemm_f32(
    const float* __restrict__ QK, const float* __restrict__ R,
    float* __restrict__ rot)
{
  __shared__ float As[16][68];
  __shared__ float Bs[16][68];
  const int bm = blockIdx.x * 64, bn = blockIdx.y * 64;
  const int tid = threadIdx.x, tx = tid & 15, ty = tid >> 4;
  float acc[4][4] = {};
  for (int k0 = 0; k0 < 512; k0 += 16) {
    {
      const int r = tid >> 2, q = tid & 3;
      float4 av = *(const float4*)(QK + (size_t)(bm + r) * 512 + k0 + q * 4);
      As[q*4+0][r]=av.x; As[q*4+1][r]=av.y; As[q*4+2][r]=av.z; As[q*4+3][r]=av.w;
    }
    {
      const int kr = tid >> 4, n4 = (tid & 15) * 4;
      *(float4*)&Bs[kr][n4] = *(const float4*)(R + (size_t)(k0 + kr) * 256 + bn + n4);
    }
    __syncthreads();
    #pragma unroll
    for (int k = 0; k < 16; ++k) {
      float a[4], bb[4];
      #pragma unroll
      for (int i = 0; i < 4; ++i) a[i] = As[k][ty*4+i];
      #pragma unroll
      for (int j = 0; j < 4; ++j) bb[j] = Bs[k][tx*4+j];
      #pragma unroll
      for (int i = 0; i < 4; ++i)
        #pragma unroll
        for (int j = 0; j < 4; ++j)
          acc[i][j] = fmaf(a[i], bb[j], acc[i][j]);
    }
    __syncthreads();
  }
  #pragma unroll
  for (int i = 0; i < 4; ++i)
    #pragma unroll
    for (int j = 0; j < 4; ++j)
      rot[(size_t)(bm + ty*4 + i) * 256 + (bn + tx*4 + j)] = acc[i][j];
}

// -------- bucket = argmax over [rot, -rot] per (token, hash) --------
__global__ __launch_bounds__(256) void argmax_kernel(
    const float* __restrict__ rot, int* __restrict__ buckets)
{
  const int tok = blockIdx.x;
  const int j = threadIdx.x;             // j = h*32 + i
  const float r = rot[(size_t)tok * 256 + j];
  float val = (r >= 0.f) ? r : -r;
  int   idx = (r >= 0.f) ? (j & 31) : (j & 31) + 32;
  #pragma unroll
  for (int off = 16; off; off >>= 1) {
    const float ov = __shfl_xor(val, off);
    const int   oi = __shfl_xor(idx, off);
    if (ov > val || (ov == val && oi < idx)) { val = ov; idx = oi; }
  }
  if ((j & 31) == 0) {
    const int h = j >> 5, b = tok >> 12, t = tok & 4095;
    buckets[((b << 3) + h) * 4096 + t] = idx;
  }
}

// -------- stable counting sort per (b,h); also emits token->sorted-pos map --------
__global__ __launch_bounds__(256) void sort_kernel(
    const int* __restrict__ buckets, int* __restrict__ st, int* __restrict__ pos)
{
  __shared__ int bk_lds[4096];
  __shared__ int cnt[4][64];
  __shared__ int startq[4][64];
  const int tid = threadIdx.x;
  const int base = blockIdx.x * 4096;     // blockIdx = b*8+h
  for (int t = tid; t < 4096; t += 256) bk_lds[t] = buckets[base + t];
  __syncthreads();
  const int wave = tid >> 6, lane = tid & 63;
  const int q0 = wave * 1024;
  int c = 0;
  for (int t = 0; t < 1024; ++t) c += (bk_lds[q0 + t] == lane);
  cnt[wave][lane] = c;
  __syncthreads();
  if (tid < 64) {
    const int c0 = cnt[0][tid], c1 = cnt[1][tid], c2 = cnt[2][tid], c3 = cnt[3][tid];
    const int tot = c0 + c1 + c2 + c3;
    int ex = tot;
    #pragma unroll
    for (int off = 1; off < 64; off <<= 1) {
      const int n = __shfl_up(ex, off);
      if (lane >= off) ex += n;
    }
    const int bucket_start = ex - tot;
    startq[0][tid] = bucket_start;
    startq[1][tid] = bucket_start + c0;
    startq[2][tid] = bucket_start + c0 + c1;
    startq[3][tid] = bucket_start + c0 + c1 + c2;
  }
  __syncthreads();
  int cur = startq[wave][lane];
  for (int t = 0; t < 1024; ++t) {
    if (bk_lds[q0 + t] == lane) {
      st[base + cur] = q0 + t;
      pos[base + q0 + t] = cur;
      cur++;
    }
  }
}

// -------- scale[token] = D^-0.5 / max(||qk_row||, 1e-12) --------
__global__ __launch_bounds__(256) void scale_kernel(
    const float* __restrict__ qk, float* __restrict__ scale)
{
  const int wave = threadIdx.x >> 6, lane = threadIdx.x & 63;
  const int tok = blockIdx.x * 4 + wave;
  const float4* row = (const float4*)(qk + (size_t)tok * 512);
  const float4 p0 = row[lane], p1 = row[lane + 64];
  float s = p0.x*p0.x + p0.y*p0.y + p0.z*p0.z + p0.w*p0.w
          + p1.x*p1.x + p1.y*p1.y + p1.z*p1.z + p1.w*p1.w;
  #pragma unroll
  for (int off = 32; off; off >>= 1) s += __shfl_down(s, off);
  if (lane == 0) {
    const float n = fmaxf(sqrtf(s), 1e-12f);
    scale[tok] = 0.044194173824159216f / n;   // 512^-0.5 / norm
  }
}

// -------- chunked attention: stores sorted-output tile (bf16), no atomics --------
// grid: B * g * 64 blocks; g = hashes in this pass, hbase = first hash.
__global__ __launch_bounds__(256) void attn_kernel_so(
    const float* __restrict__ qk, const float* __restrict__ v,
    const float* __restrict__ scale, const int* __restrict__ st,
    __hip_bfloat16* __restrict__ so, int g, int hbase)
{
  __shared__ float tile[64][133];
  __shared__ float dlds[64][68];
  __shared__ int   stt[64];
  __shared__ float scl[64];
  const int blk = blockIdx.x;
  const int cpg = g * 64;                  // chunks per batch this pass
  const int b = blk / cpg, rem = blk % cpg;
  const int hl = rem >> 6, cpos = rem & 63;
  const int tid = threadIdx.x, tx = tid & 15, ty = tid >> 4;
  if (tid < 64) {
    const int s = st[(size_t)((b * 8 + hbase + hl) * 4096) + cpos * 64 + tid];
    stt[tid] = s;
    scl[tid] = scale[b * 4096 + s];
  }
  __syncthreads();
  const int r = tid >> 2, q = tid & 3;
  const size_t rowbase = ((size_t)b * 4096 + stt[r]) * 512;
  const size_t sobase  = ((size_t)(b * g + hl) * 4096 + cpos * 64) * 512;

  float S[4][4] = {};
  for (int dt = 0; dt < 4; ++dt) {
    const float* src = qk + rowbase + dt * 128;
    #pragma unroll
    for (int s8 = 0; s8 < 8; ++s8) {
      const int col = q * 4 + s8 * 16;
      *(float4*)&tile[r][col] = *(const float4*)(src + col);
    }
    __syncthreads();
    #pragma unroll 8
    for (int k = 0; k < 128; ++k) {
      const float a0=tile[ty*4+0][k], a1=tile[ty*4+1][k], a2=tile[ty*4+2][k], a3=tile[ty*4+3][k];
      const float b0=tile[tx*4+0][k], b1=tile[tx*4+1][k], b2=tile[tx*4+2][k], b3=tile[tx*4+3][k];
      S[0][0]=fmaf(a0,b0,S[0][0]); S[0][1]=fmaf(a0,b1,S[0][1]); S[0][2]=fmaf(a0,b2,S[0][2]); S[0][3]=fmaf(a0,b3,S[0][3]);
      S[1][0]=fmaf(a1,b0,S[1][0]); S[1][1]=fmaf(a1,b1,S[1][1]); S[1][2]=fmaf(a1,b2,S[1][2]); S[1][3]=fmaf(a1,b3,S[1][3]);
      S[2][0]=fmaf(a2,b0,S[2][0]); S[2][1]=fmaf(a2,b1,S[2][1]); S[2][2]=fmaf(a2,b2,S[2][2]); S[2][3]=fmaf(a2,b3,S[2][3]);
      S[3][0]=fmaf(a3,b0,S[3][0]); S[3][1]=fmaf(a3,b1,S[3][1]); S[3][2]=fmaf(a3,b2,S[3][2]); S[3][3]=fmaf(a3,b3,S[3][3]);
    }
    __syncthreads();
  }
  #pragma unroll
  for (int i = 0; i < 4; ++i)
    #pragma unroll
    for (int j = 0; j < 4; ++j)
      dlds[ty*4+i][tx*4+j] = S[i][j] * scl[tx*4+j];
  __syncthreads();

  for (int dt = 0; dt < 4; ++dt) {
    const float* src = v + rowbase + dt * 128;
    #pragma unroll
    for (int s8 = 0; s8 < 8; ++s8) {
      const int col = q * 4 + s8 * 16;
      *(float4*)&tile[r][col] = *(const float4*)(src + col);
    }
    __syncthreads();
    float o[4][8] = {};
    #pragma unroll 4
    for (int j = 0; j < 64; ++j) {
      const float a0=dlds[ty*4+0][j], a1=dlds[ty*4+1][j], a2=dlds[ty*4+2][j], a3=dlds[ty*4+3][j];
      float bb[8];
      *(float4*)&bb[0] = *(const float4*)&tile[j][tx*8];
      *(float4*)&bb[4] = *(const float4*)&tile[j][tx*8+4];
      #pragma unroll
      for (int d = 0; d < 8; ++d) {
        o[0][d]=fmaf(a0,bb[d],o[0][d]); o[1][d]=fmaf(a1,bb[d],o[1][d]);
        o[2][d]=fmaf(a2,bb[d],o[2][d]); o[3][d]=fmaf(a3,bb[d],o[3][d]);
      }
    }
    #pragma unroll
    for (int i = 0; i < 4; ++i) {
      __hip_bfloat16 us[8];
      #pragma unroll
      for (int d = 0; d < 8; ++d) us[d] = __float2bfloat16(o[i][d]);
      __hip_bfloat16* dst = so + sobase + (size_t)(ty*4 + i) * 512 + dt * 128 + tx * 8;
      *(uint4*)dst = *(const uint4*)us;
    }
    __syncthreads();
  }
}

// -------- fallback: atomic accumulate directly into o_acc (used only if ws too small) --------
__global__ __launch_bounds__(256) void attn_kernel_atomic(
    const float* __restrict__ qk, const float* __restrict__ v,
    const float* __restrict__ scale, const int* __restrict__ st,
    float* __restrict__ o_acc)
{
  __shared__ float tile[64][133];
  __shared__ float dlds[64][68];
  __shared__ int   stt[64];
  __shared__ float scl[64];
  const int blk = blockIdx.x;
  const int b = blk >> 9, c = blk & 511;
  const int tid = threadIdx.x, tx = tid & 15, ty = tid >> 4;
  if (tid < 64) {
    const int s = st[(size_t)b * 32768 + c * 64 + tid];
    stt[tid] = s;
    scl[tid] = scale[b * 4096 + s];
  }
  __syncthreads();
  const int r = tid >> 2, q = tid & 3;
  const size_t rowbase = ((size_t)b * 4096 + stt[r]) * 512;
  float S[4][4] = {};
  for (int dt = 0; dt < 4; ++dt) {
    const float* src = qk + rowbase + dt * 128;
    #pragma unroll
    for (int s8 = 0; s8 < 8; ++s8) {
      const int col = q * 4 + s8 * 16;
      *(float4*)&tile[r][col] = *(const float4*)(src + col);
    }
    __syncthreads();
    #pragma unroll 8
    for (int k = 0; k < 128; ++k) {
      const float a0=tile[ty*4+0][k], a1=tile[ty*4+1][k], a2=tile[ty*4+2][k], a3=tile[ty*4+3][k];
      const float b0=tile[tx*4+0][k], b1=tile[tx*4+1][k], b2=tile[tx*4+2][k], b3=tile[tx*4+3][k];
      S[0][0]=fmaf(a0,b0,S[0][0]); S[0][1]=fmaf(a0,b1,S[0][1]); S[0][2]=fmaf(a0,b2,S[0][2]); S[0][3]=fmaf(a0,b3,S[0][3]);
      S[1][0]=fmaf(a1,b0,S[1][0]); S[1][1]=fmaf(a1,b1,S[1][1]); S[1][2]=fmaf(a1,b2,S[1][2]); S[1][3]=fmaf(a1,b3,S[1][3]);
      S[2][0]=fmaf(a2,b0,S[2][0]); S[2][1]=fmaf(a2,b1,S[2][1]); S[2][2]=fmaf(a2,b2,S[2][2]); S[2][3]=fmaf(a2,b3,S[2][3]);
      S[3][0]=fmaf(a3,b0,S[3][0]); S[3][1]=fmaf(a3,b1,S[3][1]); S[3][2]=fmaf(a3,b2,S[3][2]); S[3][3]=fmaf(a3,b3,S[3][3]);
    }
    __syncthreads();
  }
  #pragma unroll
  for (int i = 0; i < 4; ++i)
    #pragma unroll
    for (int j = 0; j < 4; ++j)
      dlds[ty*4+i][tx*4+j] = S[i][j] * scl[tx*4+j];
  __syncthreads();
  for (int dt = 0; dt < 4; ++dt) {
    const float* src = v + rowbase + dt * 128;
    #pragma unroll
    for (int s8 = 0; s8 < 8; ++s8) {
      const int col = q * 4 + s8 * 16;
      *(float4*)&tile[r][col] = *(const float4*)(src + col);
    }
    __syncthreads();
    float o[4][8] = {};
    #pragma unroll 4
    for (int j = 0; j < 64; ++j) {
      const float a0=dlds[ty*4+0][j], a1=dlds[ty*4+1][j], a2=dlds[ty*4+2][j], a3=dlds[ty*4+3][j];
      float bb[8];
      *(float4*)&bb[0] = *(const float4*)&tile[j][tx*8];
      *(float4*)&bb[4] = *(const float4*)&tile[j][tx*8+4];
      #pragma unroll
      for (int d = 0; d < 8; ++d) {
        o[0][d]=fmaf(a0,bb[d],o[0][d]); o[1][d]=fmaf(a1,bb[d],o[1][d]);
        o[2][d]=fmaf(a2,bb[d],o[2][d]); o[3][d]=fmaf(a3,bb[d],o[3][d]);
      }
    }
    #pragma unroll
    for (int i = 0; i < 4; ++i) {
      float* dst = o_acc + ((size_t)b * 4096 + stt[ty*4+i]) * 512 + dt * 128 + tx * 8;
      #pragma unroll
      for (int d = 0; d < 8; ++d) atomicAdd(dst + d, o[i][d]);
    }
    __syncthreads();
  }
}

// -------- gather: o_acc[b][t][:] (+)= sum_{hl<g} so[(b*g+hl)][pos[b][hbase+hl][t]][:] --------
__global__ __launch_bounds__(256) void gather_kernel(
    const __hip_bfloat16* __restrict__ so, const int* __restrict__ pos,
    float* __restrict__ o_acc, int g, int hbase, int first)
{
  const int tok = blockIdx.x;
  const int b = tok >> 12, t = tok & 4095;
  const int d0 = threadIdx.x * 2;
  float2 acc;
  float* dst = o_acc + (size_t)tok * 512 + d0;
  if (first) { acc.x = 0.f; acc.y = 0.f; }
  else       { acc = *(const float2*)dst; }
  for (int hl = 0; hl < g; ++hl) {
    const int p = pos[(size_t)((b * 8 + hbase + hl) * 4096) + t];
    const __hip_bfloat16* srow = so + ((size_t)(b * g + hl) * 4096 + p) * 512 + d0;
    acc.x += __bfloat162float(srow[0]);
    acc.y += __bfloat162float(srow[1]);
  }
  *(float2*)dst = acc;
}

extern "C" void kernel_launch(void* const* d_in, const int* in_sizes, int n_in,
                              void* d_out, int out_size, void* d_ws, size_t ws_size,
                              hipStream_t stream) {
  const float* x         = (const float*)d_in[0];
  const float* rotations = (const float*)d_in[1];
  const float* w_qk      = (const float*)d_in[2];
  const float* b_qk      = (const float*)d_in[3];
  const float* w_v       = (const float*)d_in[4];
  const float* b_v       = (const float*)d_in[5];
  const float* w_out     = (const float*)d_in[6];
  const float* b_out     = (const float*)d_in[7];
  float* out = (float*)d_out;
  char* ws = (char*)d_ws;

  float*  qk      = (float*)(ws);                     // 33.55 MB
  float*  vbuf    = (float*)(ws + 33554432);          // 33.55 MB
  float*  o_acc   = (float*)(ws + 67108864);          // 33.55 MB
  float*  rot     = o_acc;                            // alias: rot dead before o_acc lives
  float*  scale   = (float*)(ws + 100663296);         // 64 KB
  int*    buckets = (int*)(ws + 100728832);           // 512 KB
  int*    st      = (int*)(ws + 101253120);           // 512 KB
  int*    pos     = (int*)(ws + 101777408);           // 512 KB
  __hip_bfloat16* so = (__hip_bfloat16*)(ws + 102301696);  // g * 16.78 MB
  const size_t so_off = 102301696;

  int g = 0;
  for (int cand = 8; cand >= 1; cand >>= 1)
    if (so_off + (size_t)cand * 16777216ull <= ws_size) { g = cand; break; }

  const dim3 gemm_grid(128, 4), blk256(256);
  hipLaunchKernelGGL(gemm_bias_f32, gemm_grid, blk256, 0, stream, x, w_qk, b_qk, qk, 16384, 512, 512);
  hipLaunchKernelGGL(gemm_bias_f32, gemm_grid, blk256, 0, stream, x, w_v, b_v, vbuf, 16384, 512, 512);
  hipLaunchKernelGGL(rot_gemm_f32, dim3(256, 4), blk256, 0, stream, qk, rotations, rot);
  hipLaunchKernelGGL(argmax_kernel, dim3(16384), blk256, 0, stream, rot, buckets);
  hipLaunchKernelGGL(sort_kernel, dim3(32), blk256, 0, stream, buckets, st, pos);
  hipLaunchKernelGGL(scale_kernel, dim3(4096), blk256, 0, stream, qk, scale);

  if (g > 0) {
    const int passes = 8 / g;
    for (int p = 0; p < passes; ++p) {
      const int hbase = p * g;
      hipLaunchKernelGGL(attn_kernel_so, dim3(4 * g * 64), blk256, 0, stream,
                         qk, vbuf, scale, st, so, g, hbase);
      hipLaunchKernelGGL(gather_kernel, dim3(16384), blk256, 0, stream,
                         so, pos, o_acc, g, hbase, (p == 0) ? 1 : 0);
    }
  } else {
    hipMemsetAsync(o_acc, 0, 33554432, stream);
    hipLaunchKernelGGL(attn_kernel_atomic, dim3(2048), blk256, 0, stream,
                       qk, vbuf, scale, st, o_acc);
  }

  hipLaunchKernelGGL(gemm_bias_f32, gemm_grid, blk256, 0, stream, o_acc, w_out, b_out, out, 16384, 512, 512);
}

// Round 4
// 615.106 us; speedup vs baseline: 3.8942x; 1.4362x over previous
//
#include <hip/hip_runtime.h>

// LSH attention, B=4, T=4096, D=512, H=8 hashes, 64 buckets/hash, bucket size 64.
// Round 4: bf16 MFMA attention (16x16x32), XOR-swizzled LDS, transposed-V LDS
// staging, LDS-bounced coalesced so-stores, streaming gather (no pos map).
// fp32 kept for the argmax-critical path (qk GEMM, rot GEMM) and out GEMM.

typedef __attribute__((ext_vector_type(8))) short short8;
typedef __attribute__((ext_vector_type(4))) float f32x4;
typedef unsigned short ushort_t;

__device__ __forceinline__ ushort_t f2b(float f) {
  union { float f; unsigned u; } x; x.f = f;
  unsigned r = x.u + 0x7fffu + ((x.u >> 16) & 1u);
  return (ushort_t)(r >> 16);
}
__device__ __forceinline__ float b2f(ushort_t b) {
  union { unsigned u; float f; } x; x.u = ((unsigned)b) << 16;
  return x.f;
}

// ---------------- GEMM fp32: C[M,N] = A[M,K] @ W[K,N] + bias[N] ----------------
__global__ __launch_bounds__(256) void gemm_bias_f32(
    const float* __restrict__ A, const float* __restrict__ W,
    const float* __restrict__ bias, float* __restrict__ C,
    int M, int N, int K)
{
  __shared__ float As[16][136];
  __shared__ float Bs[16][136];
  const int bm = blockIdx.x * 128, bn = blockIdx.y * 128;
  const int tid = threadIdx.x, tx = tid & 15, ty = tid >> 4;
  float acc[8][8] = {};
  for (int k0 = 0; k0 < K; k0 += 16) {
    {
      const int r = tid >> 1, q = tid & 1;
      const float* src = A + (size_t)(bm + r) * K + k0 + q * 8;
      float4 v0 = *(const float4*)src;
      float4 v1 = *(const float4*)(src + 4);
      const int kk = q * 8;
      As[kk+0][r]=v0.x; As[kk+1][r]=v0.y; As[kk+2][r]=v0.z; As[kk+3][r]=v0.w;
      As[kk+4][r]=v1.x; As[kk+5][r]=v1.y; As[kk+6][r]=v1.z; As[kk+7][r]=v1.w;
    }
    {
      const int kr = tid >> 4, c4 = (tid & 15) * 4;
      const float* src = W + (size_t)(k0 + kr) * N + bn;
      *(float4*)&Bs[kr][c4]      = *(const float4*)(src + c4);
      *(float4*)&Bs[kr][c4 + 64] = *(const float4*)(src + c4 + 64);
    }
    __syncthreads();
    #pragma unroll
    for (int k = 0; k < 16; ++k) {
      float a[8], bb[8];
      *(float4*)&a[0]  = *(const float4*)&As[k][ty*8];
      *(float4*)&a[4]  = *(const float4*)&As[k][ty*8+4];
      *(float4*)&bb[0] = *(const float4*)&Bs[k][tx*8];
      *(float4*)&bb[4] = *(const float4*)&Bs[k][tx*8+4];
      #pragma unroll
      for (int i = 0; i < 8; ++i)
        #pragma unroll
        for (int j = 0; j < 8; ++j)
          acc[i][j] = fmaf(a[i], bb[j], acc[i][j]);
    }
    __syncthreads();
  }
  #pragma unroll
  for (int i = 0; i < 8; ++i) {
    const int row = bm + ty*8 + i;
    float* dst = C + (size_t)row * N + bn + tx*8;
    const float* bp = bias + bn + tx*8;
    float o[8];
    #pragma unroll
    for (int j = 0; j < 8; ++j) o[j] = acc[i][j] + bp[j];
    *(float4*)dst       = *(float4*)&o[0];
    *(float4*)(dst + 4) = *(float4*)&o[4];
  }
}

// -------- rot[16384,256] = QK[16384,512] @ R[512,256], fp32 sequential-K --------
__global__ __launch_bounds__(256) void rot_gemm_f32(
    const float* __restrict__ QK, const float* __restrict__ R,
    float* __restrict__ rot)
{
  __shared__ float As[16][68];
  __shared__ float Bs[16][68];
  const int bm = blockIdx.x * 64, bn = blockIdx.y * 64;
  const int tid = threadIdx.x, tx = tid & 15, ty = tid >> 4;
  float acc[4][4] = {};
  for (int k0 = 0; k0 < 512; k0 += 16) {
    {
      const int r = tid >> 2, q = tid & 3;
      float4 av = *(const float4*)(QK + (size_t)(bm + r) * 512 + k0 + q * 4);
      As[q*4+0][r]=av.x; As[q*4+1][r]=av.y; As[q*4+2][r]=av.z; As[q*4+3][r]=av.w;
    }
    {
      const int kr = tid >> 4, n4 = (tid & 15) * 4;
      *(float4*)&Bs[kr][n4] = *(const float4*)(R + (size_t)(k0 + kr) * 256 + bn + n4);
    }
    __syncthreads();
    #pragma unroll
    for (int k = 0; k < 16; ++k) {
      float a[4], bb[4];
      #pragma unroll
      for (int i = 0; i < 4; ++i) a[i] = As[k][ty*4+i];
      #pragma unroll
      for (int j = 0; j < 4; ++j) bb[j] = Bs[k][tx*4+j];
      #pragma unroll
      for (int i = 0; i < 4; ++i)
        #pragma unroll
        for (int j = 0; j < 4; ++j)
          acc[i][j] = fmaf(a[i], bb[j], acc[i][j]);
    }
    __syncthreads();
  }
  #pragma unroll
  for (int i = 0; i < 4; ++i)
    #pragma unroll
    for (int j = 0; j < 4; ++j)
      rot[(size_t)(bm + ty*4 + i) * 256 + (bn + tx*4 + j)] = acc[i][j];
}

// -------- bucket = argmax over [rot, -rot] per (token, hash) --------
__global__ __launch_bounds__(256) void argmax_kernel(
    const float* __restrict__ rot, int* __restrict__ buckets)
{
  const int tok = blockIdx.x;
  const int j = threadIdx.x;             // j = h*32 + i
  const float r = rot[(size_t)tok * 256 + j];
  float val = (r >= 0.f) ? r : -r;
  int   idx = (r >= 0.f) ? (j & 31) : (j & 31) + 32;
  #pragma unroll
  for (int off = 16; off; off >>= 1) {
    const float ov = __shfl_xor(val, off);
    const int   oi = __shfl_xor(idx, off);
    if (ov > val || (ov == val && oi < idx)) { val = ov; idx = oi; }
  }
  if ((j & 31) == 0) {
    const int h = j >> 5, b = tok >> 12, t = tok & 4095;
    buckets[((b << 3) + h) * 4096 + t] = idx;
  }
}

// -------- stable counting sort per (b,h): tokens by (bucket, t) --------
__global__ __launch_bounds__(256) void sort_kernel(
    const int* __restrict__ buckets, int* __restrict__ st)
{
  __shared__ int bk_lds[4096];
  __shared__ int cnt[4][64];
  __shared__ int startq[4][64];
  const int tid = threadIdx.x;
  const int base = blockIdx.x * 4096;     // blockIdx = b*8+h
  for (int t = tid; t < 4096; t += 256) bk_lds[t] = buckets[base + t];
  __syncthreads();
  const int wave = tid >> 6, lane = tid & 63;
  const int q0 = wave * 1024;
  int c = 0;
  for (int t = 0; t < 1024; ++t) c += (bk_lds[q0 + t] == lane);
  cnt[wave][lane] = c;
  __syncthreads();
  if (tid < 64) {
    const int c0 = cnt[0][tid], c1 = cnt[1][tid], c2 = cnt[2][tid], c3 = cnt[3][tid];
    const int tot = c0 + c1 + c2 + c3;
    int ex = tot;
    #pragma unroll
    for (int off = 1; off < 64; off <<= 1) {
      const int n = __shfl_up(ex, off);
      if (lane >= off) ex += n;
    }
    const int bucket_start = ex - tot;
    startq[0][tid] = bucket_start;
    startq[1][tid] = bucket_start + c0;
    startq[2][tid] = bucket_start + c0 + c1;
    startq[3][tid] = bucket_start + c0 + c1 + c2;
  }
  __syncthreads();
  int cur = startq[wave][lane];
  for (int t = 0; t < 1024; ++t) {
    if (bk_lds[q0 + t] == lane) { st[base + cur] = q0 + t; cur++; }
  }
}

// -------- scale[token] = D^-0.5 / max(||qk_row||, 1e-12) --------
__global__ __launch_bounds__(256) void scale_kernel(
    const float* __restrict__ qk, float* __restrict__ scale)
{
  const int wave = threadIdx.x >> 6, lane = threadIdx.x & 63;
  const int tok = blockIdx.x * 4 + wave;
  const float4* row = (const float4*)(qk + (size_t)tok * 512);
  const float4 p0 = row[lane], p1 = row[lane + 64];
  float s = p0.x*p0.x + p0.y*p0.y + p0.z*p0.z + p0.w*p0.w
          + p1.x*p1.x + p1.y*p1.y + p1.z*p1.z + p1.w*p1.w;
  #pragma unroll
  for (int off = 32; off; off >>= 1) s += __shfl_down(s, off);
  if (lane == 0) {
    const float n = fmaxf(sqrtf(s), 1e-12f);
    scale[tok] = 0.044194173824159216f / n;   // 512^-0.5 / norm
  }
}

// -------- f32 -> bf16 conversion (8 elems/thread) --------
__global__ __launch_bounds__(256) void cvt_bf16(
    const float* __restrict__ src, ushort_t* __restrict__ dst, int n8)
{
  const int i = blockIdx.x * 256 + threadIdx.x;
  if (i >= n8) return;
  const float4 a = *(const float4*)(src + (size_t)i * 8);
  const float4 c = *(const float4*)(src + (size_t)i * 8 + 4);
  ushort_t o[8] = { f2b(a.x), f2b(a.y), f2b(a.z), f2b(a.w),
                    f2b(c.x), f2b(c.y), f2b(c.z), f2b(c.w) };
  *(uint4*)(dst + (size_t)i * 8) = *(const uint4*)o;
}

// -------- MFMA chunked attention --------
// Per block: one chunk (64 sorted tokens). S = Q@Q^T (bf16 MFMA, fp32 acc),
// P = S*scale_j -> bf16 LDS, bo = P@V via transposed-V LDS. Output scattered
// to so[(b*g+hl)*4096 + token] (unsorted order) via LDS bounce, coalesced.
__global__ __launch_bounds__(256, 2) void attn_mfma(
    const ushort_t* __restrict__ qk_b, const ushort_t* __restrict__ v_b,
    const float* __restrict__ scale, const int* __restrict__ st,
    ushort_t* __restrict__ so, int g, int hbase)
{
  __shared__ __align__(16) char Q[32768];   // 64 x 256 bf16 (qk half; later so bounce)
  __shared__ __align__(16) char VT[32768];  // 256 x 64 bf16 (transposed V half)
  __shared__ __align__(16) char P[8192];    // 64 x 64 bf16
  __shared__ int   stt[64];
  __shared__ float scl[64];

  const int blk = blockIdx.x;
  const int cpg = g * 64;
  const int b = blk / cpg, rem = blk % cpg;
  const int hl = rem >> 6, c = rem & 63;
  const int tid = threadIdx.x, w = tid >> 6, l = tid & 63;
  const int m = l & 15, gq = l >> 4;

  if (tid < 64) {
    const int s = st[(size_t)((b * 8 + hbase + hl) * 4096) + c * 64 + tid];
    stt[tid] = s;
    scl[tid] = scale[b * 4096 + s];
  }
  __syncthreads();

  const size_t qkbase = (size_t)b * 4096;
  f32x4 accS[4] = {};

  // ---- S = Q @ Q^T over two 256-wide K halves ----
  for (int half = 0; half < 2; ++half) {
    #pragma unroll
    for (int it = 0; it < 8; ++it) {
      const int blk16 = it * 256 + tid;
      const int row = blk16 >> 5, u = blk16 & 31;
      const uint4 dat = *(const uint4*)(qk_b + (qkbase + stt[row]) * 512 + half * 256 + u * 8);
      *(uint4*)(Q + ((row * 512 + u * 16) ^ ((row & 7) << 4))) = dat;
    }
    __syncthreads();
    #pragma unroll
    for (int kf = 0; kf < 8; ++kf) {
      const int arow = w * 16 + m;
      const short8 af = *(const short8*)(Q + ((arow * 512 + kf * 64 + gq * 16) ^ ((arow & 7) << 4)));
      #pragma unroll
      for (int jt = 0; jt < 4; ++jt) {
        const int brow = jt * 16 + m;
        const short8 bf = *(const short8*)(Q + ((brow * 512 + kf * 64 + gq * 16) ^ ((brow & 7) << 4)));
        accS[jt] = __builtin_amdgcn_mfma_f32_16x16x32_bf16(af, bf, accS[jt], 0, 0, 0);
      }
    }
    __syncthreads();
  }

  // ---- P[i][j] = S[i][j] * scl[j] -> bf16 LDS ----
  // C/D layout (m89): col = lane&15, row = (lane>>4)*4 + reg
  #pragma unroll
  for (int jt = 0; jt < 4; ++jt)
    #pragma unroll
    for (int r = 0; r < 4; ++r) {
      const int i = w * 16 + gq * 4 + r;
      const int j = jt * 16 + m;
      *(ushort_t*)(P + ((i * 128 + j * 2) ^ ((i & 7) << 4))) = f2b(accS[jt][r] * scl[j]);
    }

  // ---- PV over two 256-wide d halves ----
  const size_t sobase = (size_t)(b * g + hl) * 4096;
  for (int half = 0; half < 2; ++half) {
    // stage transposed V half: VT[d][j], scalar b16 writes (one-time conflicts ok)
    #pragma unroll
    for (int it = 0; it < 8; ++it) {
      const int blk16 = it * 256 + tid;
      const int j = blk16 >> 5, u = blk16 & 31;
      const uint4 dat = *(const uint4*)(v_b + (qkbase + stt[j]) * 512 + half * 256 + u * 8);
      const ushort_t* e = (const ushort_t*)&dat;
      #pragma unroll
      for (int ee = 0; ee < 8; ++ee) {
        const int d = u * 8 + ee;
        *(ushort_t*)(VT + ((d * 128 + j * 2) ^ (((d ^ (d >> 3)) & 7) << 4))) = e[ee];
      }
    }
    __syncthreads();   // VT (and P on first iter) ready

    short8 ap[2];
    #pragma unroll
    for (int kf = 0; kf < 2; ++kf) {
      const int i = w * 16 + m;
      ap[kf] = *(const short8*)(P + ((i * 128 + kf * 64 + gq * 16) ^ ((i & 7) << 4)));
    }
    f32x4 accO[16] = {};
    #pragma unroll
    for (int dt = 0; dt < 16; ++dt) {
      #pragma unroll
      for (int kf = 0; kf < 2; ++kf) {
        const int d = dt * 16 + m;
        const short8 bv = *(const short8*)(VT + ((d * 128 + kf * 64 + gq * 16) ^ (((d ^ (d >> 3)) & 7) << 4)));
        accO[dt] = __builtin_amdgcn_mfma_f32_16x16x32_bf16(ap[kf], bv, accO[dt], 0, 0, 0);
      }
    }
    __syncthreads();   // all PV reads done; Q free for bounce

    #pragma unroll
    for (int dt = 0; dt < 16; ++dt)
      #pragma unroll
      for (int r = 0; r < 4; ++r) {
        const int i = w * 16 + gq * 4 + r;
        const int dcol = dt * 16 + m;
        *(ushort_t*)(Q + ((i * 512 + dcol * 2) ^ ((i & 7) << 4))) = f2b(accO[dt][r]);
      }
    __syncthreads();

    // coalesced scatter-flush: row -> so[sobase + stt[row]]
    #pragma unroll
    for (int it = 0; it < 8; ++it) {
      const int blk16 = it * 256 + tid;
      const int row = blk16 >> 5, u = blk16 & 31;
      const uint4 dat = *(const uint4*)(Q + ((row * 512 + u * 16) ^ ((row & 7) << 4)));
      *(uint4*)(so + (sobase + stt[row]) * 512 + half * 256 + u * 8) = dat;
    }
  }
}

// -------- gather: o_acc[b][t][:] (+)= sum_{hl<g} so[(b*g+hl)*4096 + t][:] --------
__global__ __launch_bounds__(256) void gather_kernel(
    const ushort_t* __restrict__ so, float* __restrict__ o_acc, int g, int first)
{
  const int tok = blockIdx.x;
  const int b = tok >> 12, t = tok & 4095;
  const int d0 = threadIdx.x * 2;
  float* dst = o_acc + (size_t)tok * 512 + d0;
  float ax, ay;
  if (first) { ax = 0.f; ay = 0.f; }
  else       { float2 p = *(const float2*)dst; ax = p.x; ay = p.y; }
  const size_t stride = (size_t)4096 * 512;
  const ushort_t* src = so + ((size_t)(b * g) * 4096 + t) * 512 + d0;
  for (int hlp = 0; hlp < g; ++hlp) {
    const unsigned u = *(const unsigned*)src;
    ax += b2f((ushort_t)(u & 0xffff));
    ay += b2f((ushort_t)(u >> 16));
    src += stride;
  }
  float2 o; o.x = ax; o.y = ay;
  *(float2*)dst = o;
}

extern "C" void kernel_launch(void* const* d_in, const int* in_sizes, int n_in,
                              void* d_out, int out_size, void* d_ws, size_t ws_size,
                              hipStream_t stream) {
  const float* x         = (const float*)d_in[0];
  const float* rotations = (const float*)d_in[1];
  const float* w_qk      = (const float*)d_in[2];
  const float* b_qk      = (const float*)d_in[3];
  const float* w_v       = (const float*)d_in[4];
  const float* b_v       = (const float*)d_in[5];
  const float* w_out     = (const float*)d_in[6];
  const float* b_out     = (const float*)d_in[7];
  float* out = (float*)d_out;
  char* ws = (char*)d_ws;

  float*    qk      = (float*)(ws);                     // 33.55 MB
  float*    vbuf    = (float*)(ws + 33554432);          // 33.55 MB
  float*    o_acc   = (float*)(ws + 67108864);          // 33.55 MB
  float*    rot     = o_acc;                            // alias: dead before o_acc lives
  float*    scale   = (float*)(ws + 100663296);         // 64 KB
  int*      buckets = (int*)(ws + 100728832);           // 512 KB
  int*      st      = (int*)(ws + 101253120);           // 512 KB
  ushort_t* qk_b    = (ushort_t*)(ws + 101777408);      // 16.78 MB
  ushort_t* v_b     = (ushort_t*)(ws + 118554624);      // 16.78 MB
  ushort_t* so      = (ushort_t*)(ws + 135331840);      // g * 16.78 MB
  const size_t so_off = 135331840;

  int g = 1;
  for (int cand = 8; cand >= 1; cand >>= 1)
    if (so_off + (size_t)cand * 16777216ull <= ws_size) { g = cand; break; }

  const dim3 gemm_grid(128, 4), blk256(256);
  hipLaunchKernelGGL(gemm_bias_f32, gemm_grid, blk256, 0, stream, x, w_qk, b_qk, qk, 16384, 512, 512);
  hipLaunchKernelGGL(gemm_bias_f32, gemm_grid, blk256, 0, stream, x, w_v, b_v, vbuf, 16384, 512, 512);
  hipLaunchKernelGGL(rot_gemm_f32, dim3(256, 4), blk256, 0, stream, qk, rotations, rot);
  hipLaunchKernelGGL(argmax_kernel, dim3(16384), blk256, 0, stream, rot, buckets);
  hipLaunchKernelGGL(sort_kernel, dim3(32), blk256, 0, stream, buckets, st);
  hipLaunchKernelGGL(scale_kernel, dim3(4096), blk256, 0, stream, qk, scale);
  hipLaunchKernelGGL(cvt_bf16, dim3(4096), blk256, 0, stream, qk, qk_b, 1048576);
  hipLaunchKernelGGL(cvt_bf16, dim3(4096), blk256, 0, stream, vbuf, v_b, 1048576);

  const int passes = 8 / g;
  for (int p = 0; p < passes; ++p) {
    const int hbase = p * g;
    hipLaunchKernelGGL(attn_mfma, dim3(4 * g * 64), blk256, 0, stream,
                       qk_b, v_b, scale, st, so, g, hbase);
    hipLaunchKernelGGL(gather_kernel, dim3(16384), blk256, 0, stream,
                       so, o_acc, g, (p == 0) ? 1 : 0);
  }

  hipLaunchKernelGGL(gemm_bias_f32, gemm_grid, blk256, 0, stream, o_acc, w_out, b_out, out, 16384, 512, 512);
}

// Round 5
// 419.805 us; speedup vs baseline: 5.7059x; 1.4652x over previous
//
#include <hip/hip_runtime.h>

// LSH attention, B=4, T=4096, D=512, H=8 hashes, 64 buckets/hash, bucket size 64.
// Round 5: qk GEMM stays bit-exact fp32 (argmax-critical) but re-tiled 64x128
// (grid 1024, conflict-free tx*4 reads, fused bf16 epilogue). v GEMM and out
// GEMM move to bf16 MFMA (continuous error path). Gather emits bf16 o_b.

typedef __attribute__((ext_vector_type(8))) short short8;
typedef __attribute__((ext_vector_type(4))) float f32x4;
typedef unsigned short ushort_t;

__device__ __forceinline__ ushort_t f2b(float f) {
  union { float f; unsigned u; } x; x.f = f;
  unsigned r = x.u + 0x7fffu + ((x.u >> 16) & 1u);
  return (ushort_t)(r >> 16);
}
__device__ __forceinline__ float b2f(unsigned b) {
  union { unsigned u; float f; } x; x.u = b << 16;
  return x.f;
}

// ---- qk GEMM fp32: C[16384,512] = A @ W + bias, bit-exact sequential-k chain ----
// 64x128 tile, grid (256,4). Also writes bf16 copy Cb (fused cvt).
__global__ __launch_bounds__(256) void gemm_qk_f32(
    const float* __restrict__ A, const float* __restrict__ W,
    const float* __restrict__ bias, float* __restrict__ C,
    ushort_t* __restrict__ Cb)
{
  __shared__ float As[16][68];
  __shared__ float Bs[16][136];
  const int bm = blockIdx.x * 64, bn = blockIdx.y * 128;
  const int tid = threadIdx.x, tx = tid & 15, ty = tid >> 4;
  float acc[4][8] = {};
  for (int k0 = 0; k0 < 512; k0 += 16) {
    {
      const int r = tid >> 2, q = tid & 3;
      const float4 av = *(const float4*)(A + (size_t)(bm + r) * 512 + k0 + q * 4);
      As[q*4+0][r] = av.x; As[q*4+1][r] = av.y; As[q*4+2][r] = av.z; As[q*4+3][r] = av.w;
    }
    {
      const int kr = tid >> 4, c4 = (tid & 15) * 4;
      const float* src = W + (size_t)(k0 + kr) * 512 + bn;
      *(float4*)&Bs[kr][c4]      = *(const float4*)(src + c4);
      *(float4*)&Bs[kr][c4 + 64] = *(const float4*)(src + c4 + 64);
    }
    __syncthreads();
    #pragma unroll
    for (int k = 0; k < 16; ++k) {
      float a[4], b0[4], b1[4];
      *(float4*)a  = *(const float4*)&As[k][ty*4];
      *(float4*)b0 = *(const float4*)&Bs[k][tx*4];
      *(float4*)b1 = *(const float4*)&Bs[k][tx*4+64];
      #pragma unroll
      for (int i = 0; i < 4; ++i)
        #pragma unroll
        for (int j = 0; j < 4; ++j) {
          acc[i][j]   = fmaf(a[i], b0[j], acc[i][j]);
          acc[i][j+4] = fmaf(a[i], b1[j], acc[i][j+4]);
        }
    }
    __syncthreads();
  }
  #pragma unroll
  for (int i = 0; i < 4; ++i) {
    const int row = bm + ty*4 + i;
    float o0[4], o1[4];
    #pragma unroll
    for (int j = 0; j < 4; ++j) {
      o0[j] = acc[i][j]   + bias[bn + tx*4 + j];
      o1[j] = acc[i][j+4] + bias[bn + tx*4 + 64 + j];
    }
    float* dst = C + (size_t)row * 512 + bn;
    *(float4*)(dst + tx*4)      = *(float4*)o0;
    *(float4*)(dst + tx*4 + 64) = *(float4*)o1;
    ushort_t ob[8] = { f2b(o0[0]), f2b(o0[1]), f2b(o0[2]), f2b(o0[3]),
                       f2b(o1[0]), f2b(o1[1]), f2b(o1[2]), f2b(o1[3]) };
    ushort_t* db = Cb + (size_t)row * 512 + bn;
    *(uint2*)(db + tx*4)      = *(const uint2*)&ob[0];
    *(uint2*)(db + tx*4 + 64) = *(const uint2*)&ob[4];
  }
}

// ---- bf16 MFMA GEMM: C[M,512] = A_bf16 @ W + bias, W given transposed (Wt[n][k]) ----
// 128x128 tile, BK=64, 4 waves; D = A·B^T with both fragments as row-slices.
__global__ __launch_bounds__(256, 2) void gemm_mfma(
    const ushort_t* __restrict__ A, const ushort_t* __restrict__ Wt,
    const float* __restrict__ bias, float* __restrict__ Cf,
    ushort_t* __restrict__ Cb, int out_bf16)
{
  __shared__ __align__(16) char Al[16384];  // 128 rows x 128 B (64 bf16), XOR-swizzled
  __shared__ __align__(16) char Bl[16384];
  const int bm = blockIdx.x * 128, bn = blockIdx.y * 128;
  const int tid = threadIdx.x, w = tid >> 6, l = tid & 63;
  const int m = l & 15, gq = l >> 4;
  f32x4 acc[2][8] = {};
  for (int k0 = 0; k0 < 512; k0 += 64) {
    const int r = tid >> 1, q = tid & 1;
    const ushort_t* srcA = A  + (size_t)(bm + r) * 512 + k0 + q * 32;
    const ushort_t* srcB = Wt + (size_t)(bn + r) * 512 + k0 + q * 32;
    #pragma unroll
    for (int i = 0; i < 4; ++i) {
      const uint4 da = *(const uint4*)(srcA + i * 8);
      *(uint4*)(Al + ((r * 128 + q * 64 + i * 16) ^ ((r & 7) << 4))) = da;
      const uint4 db = *(const uint4*)(srcB + i * 8);
      *(uint4*)(Bl + ((r * 128 + q * 64 + i * 16) ^ ((r & 7) << 4))) = db;
    }
    __syncthreads();
    #pragma unroll
    for (int ks = 0; ks < 2; ++ks) {
      short8 bfr[8];
      #pragma unroll
      for (int tj = 0; tj < 8; ++tj) {
        const int brow = tj * 16 + m;
        bfr[tj] = *(const short8*)(Bl + ((brow * 128 + ks * 64 + gq * 16) ^ ((brow & 7) << 4)));
      }
      #pragma unroll
      for (int ti = 0; ti < 2; ++ti) {
        const int arow = w * 32 + ti * 16 + m;
        const short8 af = *(const short8*)(Al + ((arow * 128 + ks * 64 + gq * 16) ^ ((arow & 7) << 4)));
        #pragma unroll
        for (int tj = 0; tj < 8; ++tj)
          acc[ti][tj] = __builtin_amdgcn_mfma_f32_16x16x32_bf16(af, bfr[tj], acc[ti][tj], 0, 0, 0);
      }
    }
    __syncthreads();
  }
  #pragma unroll
  for (int ti = 0; ti < 2; ++ti)
    #pragma unroll
    for (int tj = 0; tj < 8; ++tj) {
      const int col = bn + tj * 16 + m;
      const float bv = bias[col];
      #pragma unroll
      for (int r2 = 0; r2 < 4; ++r2) {
        const int row = bm + w * 32 + ti * 16 + gq * 4 + r2;
        const float oo = acc[ti][tj][r2] + bv;
        if (out_bf16) Cb[(size_t)row * 512 + col] = f2b(oo);
        else          Cf[(size_t)row * 512 + col] = oo;
      }
    }
}

// ---- transpose + cvt: Wt[n][k] = bf16(W[k][n]), 512x512 ----
__global__ __launch_bounds__(256) void transpose_cvt(
    const float* __restrict__ W, ushort_t* __restrict__ Wt)
{
  __shared__ float t[32][33];
  const int bx = blockIdx.x * 32, by = blockIdx.y * 32;
  const int tx = threadIdx.x & 31, ty = threadIdx.x >> 5;
  #pragma unroll
  for (int j = 0; j < 4; ++j)
    t[ty + j*8][tx] = W[(size_t)(by + ty + j*8) * 512 + bx + tx];
  __syncthreads();
  #pragma unroll
  for (int j = 0; j < 4; ++j)
    Wt[(size_t)(bx + ty + j*8) * 512 + by + tx] = f2b(t[tx][ty + j*8]);
}

// -------- rot[16384,256] = QK[16384,512] @ R[512,256], fp32 sequential-K --------
__global__ __launch_bounds__(256) void rot_gemm_f32(
    const float* __restrict__ QK, const float* __restrict__ R,
    float* __restrict__ rot)
{
  __shared__ float As[16][68];
  __shared__ float Bs[16][68];
  const int bm = blockIdx.x * 64, bn = blockIdx.y * 64;
  const int tid = threadIdx.x, tx = tid & 15, ty = tid >> 4;
  float acc[4][4] = {};
  for (int k0 = 0; k0 < 512; k0 += 16) {
    {
      const int r = tid >> 2, q = tid & 3;
      float4 av = *(const float4*)(QK + (size_t)(bm + r) * 512 + k0 + q * 4);
      As[q*4+0][r]=av.x; As[q*4+1][r]=av.y; As[q*4+2][r]=av.z; As[q*4+3][r]=av.w;
    }
    {
      const int kr = tid >> 4, n4 = (tid & 15) * 4;
      *(float4*)&Bs[kr][n4] = *(const float4*)(R + (size_t)(k0 + kr) * 256 + bn + n4);
    }
    __syncthreads();
    #pragma unroll
    for (int k = 0; k < 16; ++k) {
      float a[4], bb[4];
      #pragma unroll
      for (int i = 0; i < 4; ++i) a[i] = As[k][ty*4+i];
      #pragma unroll
      for (int j = 0; j < 4; ++j) bb[j] = Bs[k][tx*4+j];
      #pragma unroll
      for (int i = 0; i < 4; ++i)
        #pragma unroll
        for (int j = 0; j < 4; ++j)
          acc[i][j] = fmaf(a[i], bb[j], acc[i][j]);
    }
    __syncthreads();
  }
  #pragma unroll
  for (int i = 0; i < 4; ++i)
    #pragma unroll
    for (int j = 0; j < 4; ++j)
      rot[(size_t)(bm + ty*4 + i) * 256 + (bn + tx*4 + j)] = acc[i][j];
}

// -------- bucket = argmax over [rot, -rot] per (token, hash) --------
__global__ __launch_bounds__(256) void argmax_kernel(
    const float* __restrict__ rot, int* __restrict__ buckets)
{
  const int tok = blockIdx.x;
  const int j = threadIdx.x;             // j = h*32 + i
  const float r = rot[(size_t)tok * 256 + j];
  float val = (r >= 0.f) ? r : -r;
  int   idx = (r >= 0.f) ? (j & 31) : (j & 31) + 32;
  #pragma unroll
  for (int off = 16; off; off >>= 1) {
    const float ov = __shfl_xor(val, off);
    const int   oi = __shfl_xor(idx, off);
    if (ov > val || (ov == val && oi < idx)) { val = ov; idx = oi; }
  }
  if ((j & 31) == 0) {
    const int h = j >> 5, b = tok >> 12, t = tok & 4095;
    buckets[((b << 3) + h) * 4096 + t] = idx;
  }
}

// -------- stable counting sort per (b,h): tokens by (bucket, t) --------
__global__ __launch_bounds__(256) void sort_kernel(
    const int* __restrict__ buckets, int* __restrict__ st)
{
  __shared__ int bk_lds[4096];
  __shared__ int cnt[4][64];
  __shared__ int startq[4][64];
  const int tid = threadIdx.x;
  const int base = blockIdx.x * 4096;     // blockIdx = b*8+h
  for (int t = tid; t < 4096; t += 256) bk_lds[t] = buckets[base + t];
  __syncthreads();
  const int wave = tid >> 6, lane = tid & 63;
  const int q0 = wave * 1024;
  int c = 0;
  for (int t = 0; t < 1024; ++t) c += (bk_lds[q0 + t] == lane);
  cnt[wave][lane] = c;
  __syncthreads();
  if (tid < 64) {
    const int c0 = cnt[0][tid], c1 = cnt[1][tid], c2 = cnt[2][tid], c3 = cnt[3][tid];
    const int tot = c0 + c1 + c2 + c3;
    int ex = tot;
    #pragma unroll
    for (int off = 1; off < 64; off <<= 1) {
      const int n = __shfl_up(ex, off);
      if (lane >= off) ex += n;
    }
    const int bucket_start = ex - tot;
    startq[0][tid] = bucket_start;
    startq[1][tid] = bucket_start + c0;
    startq[2][tid] = bucket_start + c0 + c1;
    startq[3][tid] = bucket_start + c0 + c1 + c2;
  }
  __syncthreads();
  int cur = startq[wave][lane];
  for (int t = 0; t < 1024; ++t) {
    if (bk_lds[q0 + t] == lane) { st[base + cur] = q0 + t; cur++; }
  }
}

// -------- scale[token] = D^-0.5 / max(||qk_row||, 1e-12) --------
__global__ __launch_bounds__(256) void scale_kernel(
    const float* __restrict__ qk, float* __restrict__ scale)
{
  const int wave = threadIdx.x >> 6, lane = threadIdx.x & 63;
  const int tok = blockIdx.x * 4 + wave;
  const float4* row = (const float4*)(qk + (size_t)tok * 512);
  const float4 p0 = row[lane], p1 = row[lane + 64];
  float s = p0.x*p0.x + p0.y*p0.y + p0.z*p0.z + p0.w*p0.w
          + p1.x*p1.x + p1.y*p1.y + p1.z*p1.z + p1.w*p1.w;
  #pragma unroll
  for (int off = 32; off; off >>= 1) s += __shfl_down(s, off);
  if (lane == 0) {
    const float n = fmaxf(sqrtf(s), 1e-12f);
    scale[tok] = 0.044194173824159216f / n;   // 512^-0.5 / norm
  }
}

// -------- f32 -> bf16 conversion (8 elems/thread) --------
__global__ __launch_bounds__(256) void cvt_bf16(
    const float* __restrict__ src, ushort_t* __restrict__ dst, int n8)
{
  const int i = blockIdx.x * 256 + threadIdx.x;
  if (i >= n8) return;
  const float4 a = *(const float4*)(src + (size_t)i * 8);
  const float4 c = *(const float4*)(src + (size_t)i * 8 + 4);
  ushort_t o[8] = { f2b(a.x), f2b(a.y), f2b(a.z), f2b(a.w),
                    f2b(c.x), f2b(c.y), f2b(c.z), f2b(c.w) };
  *(uint4*)(dst + (size_t)i * 8) = *(const uint4*)o;
}

// -------- MFMA chunked attention (unchanged from round 4) --------
__global__ __launch_bounds__(256, 2) void attn_mfma(
    const ushort_t* __restrict__ qk_b, const ushort_t* __restrict__ v_b,
    const float* __restrict__ scale, const int* __restrict__ st,
    ushort_t* __restrict__ so, int g, int hbase)
{
  __shared__ __align__(16) char Q[32768];   // 64 x 256 bf16 (qk half; later so bounce)
  __shared__ __align__(16) char VT[32768];  // 256 x 64 bf16 (transposed V half)
  __shared__ __align__(16) char P[8192];    // 64 x 64 bf16
  __shared__ int   stt[64];
  __shared__ float scl[64];

  const int blk = blockIdx.x;
  const int cpg = g * 64;
  const int b = blk / cpg, rem = blk % cpg;
  const int hl = rem >> 6, c = rem & 63;
  const int tid = threadIdx.x, w = tid >> 6, l = tid & 63;
  const int m = l & 15, gq = l >> 4;

  if (tid < 64) {
    const int s = st[(size_t)((b * 8 + hbase + hl) * 4096) + c * 64 + tid];
    stt[tid] = s;
    scl[tid] = scale[b * 4096 + s];
  }
  __syncthreads();

  const size_t qkbase = (size_t)b * 4096;
  f32x4 accS[4] = {};

  for (int half = 0; half < 2; ++half) {
    #pragma unroll
    for (int it = 0; it < 8; ++it) {
      const int blk16 = it * 256 + tid;
      const int row = blk16 >> 5, u = blk16 & 31;
      const uint4 dat = *(const uint4*)(qk_b + (qkbase + stt[row]) * 512 + half * 256 + u * 8);
      *(uint4*)(Q + ((row * 512 + u * 16) ^ ((row & 7) << 4))) = dat;
    }
    __syncthreads();
    #pragma unroll
    for (int kf = 0; kf < 8; ++kf) {
      const int arow = w * 16 + m;
      const short8 af = *(const short8*)(Q + ((arow * 512 + kf * 64 + gq * 16) ^ ((arow & 7) << 4)));
      #pragma unroll
      for (int jt = 0; jt < 4; ++jt) {
        const int brow = jt * 16 + m;
        const short8 bf = *(const short8*)(Q + ((brow * 512 + kf * 64 + gq * 16) ^ ((brow & 7) << 4)));
        accS[jt] = __builtin_amdgcn_mfma_f32_16x16x32_bf16(af, bf, accS[jt], 0, 0, 0);
      }
    }
    __syncthreads();
  }

  #pragma unroll
  for (int jt = 0; jt < 4; ++jt)
    #pragma unroll
    for (int r = 0; r < 4; ++r) {
      const int i = w * 16 + gq * 4 + r;
      const int j = jt * 16 + m;
      *(ushort_t*)(P + ((i * 128 + j * 2) ^ ((i & 7) << 4))) = f2b(accS[jt][r] * scl[j]);
    }

  const size_t sobase = (size_t)(b * g + hl) * 4096;
  for (int half = 0; half < 2; ++half) {
    #pragma unroll
    for (int it = 0; it < 8; ++it) {
      const int blk16 = it * 256 + tid;
      const int j = blk16 >> 5, u = blk16 & 31;
      const uint4 dat = *(const uint4*)(v_b + (qkbase + stt[j]) * 512 + half * 256 + u * 8);
      const ushort_t* e = (const ushort_t*)&dat;
      #pragma unroll
      for (int ee = 0; ee < 8; ++ee) {
        const int d = u * 8 + ee;
        *(ushort_t*)(VT + ((d * 128 + j * 2) ^ (((d ^ (d >> 3)) & 7) << 4))) = e[ee];
      }
    }
    __syncthreads();

    short8 ap[2];
    #pragma unroll
    for (int kf = 0; kf < 2; ++kf) {
      const int i = w * 16 + m;
      ap[kf] = *(const short8*)(P + ((i * 128 + kf * 64 + gq * 16) ^ ((i & 7) << 4)));
    }
    f32x4 accO[16] = {};
    #pragma unroll
    for (int dt = 0; dt < 16; ++dt) {
      #pragma unroll
      for (int kf = 0; kf < 2; ++kf) {
        const int d = dt * 16 + m;
        const short8 bv = *(const short8*)(VT + ((d * 128 + kf * 64 + gq * 16) ^ (((d ^ (d >> 3)) & 7) << 4)));
        accO[dt] = __builtin_amdgcn_mfma_f32_16x16x32_bf16(ap[kf], bv, accO[dt], 0, 0, 0);
      }
    }
    __syncthreads();

    #pragma unroll
    for (int dt = 0; dt < 16; ++dt)
      #pragma unroll
      for (int r = 0; r < 4; ++r) {
        const int i = w * 16 + gq * 4 + r;
        const int dcol = dt * 16 + m;
        *(ushort_t*)(Q + ((i * 512 + dcol * 2) ^ ((i & 7) << 4))) = f2b(accO[dt][r]);
      }
    __syncthreads();

    #pragma unroll
    for (int it = 0; it < 8; ++it) {
      const int blk16 = it * 256 + tid;
      const int row = blk16 >> 5, u = blk16 & 31;
      const uint4 dat = *(const uint4*)(Q + ((row * 512 + u * 16) ^ ((row & 7) << 4)));
      *(uint4*)(so + (sobase + stt[row]) * 512 + half * 256 + u * 8) = dat;
    }
  }
}

// -------- gather: o_b[b][t][:] (+)= sum_{hl<g} so[(b*g+hl)*4096 + t][:], bf16 out --------
__global__ __launch_bounds__(256) void gather_kernel(
    const ushort_t* __restrict__ so, ushort_t* __restrict__ o_b, int g, int first)
{
  const int tok = blockIdx.x;
  const int b = tok >> 12, t = tok & 4095;
  const int d0 = threadIdx.x * 2;
  ushort_t* dst = o_b + (size_t)tok * 512 + d0;
  float ax = 0.f, ay = 0.f;
  if (!first) {
    const unsigned u = *(const unsigned*)dst;
    ax = b2f(u & 0xffffu); ay = b2f(u >> 16);
  }
  const size_t stride = (size_t)4096 * 512;
  const ushort_t* src = so + ((size_t)(b * g) * 4096 + t) * 512 + d0;
  for (int hlp = 0; hlp < g; ++hlp) {
    const unsigned u = *(const unsigned*)src;
    ax += b2f(u & 0xffffu);
    ay += b2f(u >> 16);
    src += stride;
  }
  *(unsigned*)dst = ((unsigned)f2b(ay) << 16) | (unsigned)f2b(ax);
}

extern "C" void kernel_launch(void* const* d_in, const int* in_sizes, int n_in,
                              void* d_out, int out_size, void* d_ws, size_t ws_size,
                              hipStream_t stream) {
  const float* x         = (const float*)d_in[0];
  const float* rotations = (const float*)d_in[1];
  const float* w_qk      = (const float*)d_in[2];
  const float* b_qk      = (const float*)d_in[3];
  const float* w_v       = (const float*)d_in[4];
  const float* b_v       = (const float*)d_in[5];
  const float* w_out     = (const float*)d_in[6];
  const float* b_out     = (const float*)d_in[7];
  float* out = (float*)d_out;
  char* ws = (char*)d_ws;

  float*    qk      = (float*)(ws);                     // 33.55 MB fp32
  ushort_t* x_b     = (ushort_t*)(ws + 33554432);       // 16.78 MB
  ushort_t* qk_b    = (ushort_t*)(ws + 50331648);       // 16.78 MB
  ushort_t* v_b     = (ushort_t*)(ws + 67108864);       // 16.78 MB
  float*    rot     = (float*)(ws + 83886080);          // 16.78 MB (dead after argmax)
  ushort_t* o_b     = (ushort_t*)(ws + 83886080);       // alias: lives after gather
  ushort_t* wvT     = (ushort_t*)(ws + 100663296);      // 512 KB
  ushort_t* woT     = (ushort_t*)(ws + 101187584);      // 512 KB
  float*    scale   = (float*)(ws + 101711872);         // 64 KB
  int*      buckets = (int*)(ws + 101777408);           // 512 KB
  int*      st      = (int*)(ws + 102301696);           // 512 KB
  ushort_t* so      = (ushort_t*)(ws + 102825984);      // g * 16.78 MB
  const size_t so_off = 102825984;

  int g = 1;
  for (int cand = 8; cand >= 1; cand >>= 1)
    if (so_off + (size_t)cand * 16777216ull <= ws_size) { g = cand; break; }

  const dim3 blk256(256);
  hipLaunchKernelGGL(gemm_qk_f32, dim3(256, 4), blk256, 0, stream, x, w_qk, b_qk, qk, qk_b);
  hipLaunchKernelGGL(cvt_bf16, dim3(4096), blk256, 0, stream, x, x_b, 1048576);
  hipLaunchKernelGGL(transpose_cvt, dim3(16, 16), blk256, 0, stream, w_v, wvT);
  hipLaunchKernelGGL(transpose_cvt, dim3(16, 16), blk256, 0, stream, w_out, woT);
  hipLaunchKernelGGL(gemm_mfma, dim3(128, 4), blk256, 0, stream, x_b, wvT, b_v, (float*)0, v_b, 1);
  hipLaunchKernelGGL(rot_gemm_f32, dim3(256, 4), blk256, 0, stream, qk, rotations, rot);
  hipLaunchKernelGGL(argmax_kernel, dim3(16384), blk256, 0, stream, rot, buckets);
  hipLaunchKernelGGL(sort_kernel, dim3(32), blk256, 0, stream, buckets, st);
  hipLaunchKernelGGL(scale_kernel, dim3(4096), blk256, 0, stream, qk, scale);

  const int passes = 8 / g;
  for (int p = 0; p < passes; ++p) {
    const int hbase = p * g;
    hipLaunchKernelGGL(attn_mfma, dim3(4 * g * 64), blk256, 0, stream,
                       qk_b, v_b, scale, st, so, g, hbase);
    hipLaunchKernelGGL(gather_kernel, dim3(16384), blk256, 0, stream,
                       so, o_b, g, (p == 0) ? 1 : 0);
  }

  hipLaunchKernelGGL(gemm_mfma, dim3(128, 4), blk256, 0, stream, o_b, woT, b_out, out, (ushort_t*)0, 0);
}

// Round 6
// 412.978 us; speedup vs baseline: 5.8002x; 1.0165x over previous
//
#include <hip/hip_runtime.h>

// LSH attention, B=4, T=4096, D=512, H=8 hashes, 64 buckets/hash, bucket size 64.
// Round 6: (a) qk GEMM rebalanced to 8x8 micro-tile + double-buffered LDS
// (LDS:FMA = 128:128 clk, was 96:64) with fused bf16 hi/lo split epilogue and
// fused x->bf16; (b) rot moved off fp32 VALU: split-bf16 MFMA (4 products)
// + top2-margin argmax + exact np-chain fallback for marginal pairs only.

typedef __attribute__((ext_vector_type(8))) short short8;
typedef __attribute__((ext_vector_type(4))) float f32x4;
typedef unsigned short ushort_t;

__device__ __forceinline__ ushort_t f2b(float f) {
  union { float f; unsigned u; } x; x.f = f;
  unsigned r = x.u + 0x7fffu + ((x.u >> 16) & 1u);
  return (ushort_t)(r >> 16);
}
__device__ __forceinline__ float b2f(unsigned b) {
  union { unsigned u; float f; } x; x.u = b << 16;
  return x.f;
}

// ---- qk GEMM fp32, bit-exact sequential-k chain; 128x128 tile, 8x8 micro ----
// Outputs: qk_hi/qk_lo (bf16 split of fp32 result); y==0 blocks also write x_b.
__global__ __launch_bounds__(256) void gemm_qk_f32(
    const float* __restrict__ A, const float* __restrict__ W,
    const float* __restrict__ bias,
    ushort_t* __restrict__ Chi, ushort_t* __restrict__ Clo,
    ushort_t* __restrict__ xb_or_null)
{
  __shared__ float As[2][16][132];
  __shared__ float Bs[2][16][132];
  const int bm = blockIdx.x * 128, bn = blockIdx.y * 128;
  const int tid = threadIdx.x, tx = tid & 15, ty = tid >> 4;
  const int ar = tid >> 1, aq = tid & 1;          // A staging: row, k-half
  const int bkr = tid >> 4, bc = (tid & 15) * 8;  // B staging: k-row, col
  ushort_t* xb = xb_or_null;
  float acc[8][8] = {};
  float4 a0v, a1v, b0v, b1v;

#define QK_LOAD(K0) { \
    const float* sA = A + (size_t)(bm + ar) * 512 + (K0) + aq * 8; \
    a0v = *(const float4*)sA; a1v = *(const float4*)(sA + 4); \
    const float* sB = W + (size_t)((K0) + bkr) * 512 + bn + bc; \
    b0v = *(const float4*)sB; b1v = *(const float4*)(sB + 4); \
    if (xb) { ushort_t xo[8] = { f2b(a0v.x), f2b(a0v.y), f2b(a0v.z), f2b(a0v.w), \
                                 f2b(a1v.x), f2b(a1v.y), f2b(a1v.z), f2b(a1v.w) }; \
      *(uint4*)(xb + (size_t)(bm + ar) * 512 + (K0) + aq * 8) = *(const uint4*)xo; } }

#define QK_STORE(P) { \
    As[P][aq*8+0][ar] = a0v.x; As[P][aq*8+1][ar] = a0v.y; \
    As[P][aq*8+2][ar] = a0v.z; As[P][aq*8+3][ar] = a0v.w; \
    As[P][aq*8+4][ar] = a1v.x; As[P][aq*8+5][ar] = a1v.y; \
    As[P][aq*8+6][ar] = a1v.z; As[P][aq*8+7][ar] = a1v.w; \
    *(float4*)&Bs[P][bkr][bc]     = b0v; \
    *(float4*)&Bs[P][bkr][bc + 4] = b1v; }

  QK_LOAD(0) QK_STORE(0) QK_LOAD(16)
  __syncthreads();
  for (int t = 0; t < 32; ++t) {
    const int cur = t & 1;
    if (t < 31) QK_STORE(cur ^ 1)
    if (t < 30) QK_LOAD((t + 2) * 16)
    #pragma unroll
    for (int k = 0; k < 16; ++k) {
      float a[8], b[8];
      *(float4*)&a[0] = *(const float4*)&As[cur][k][ty*4];
      *(float4*)&a[4] = *(const float4*)&As[cur][k][ty*4 + 64];
      *(float4*)&b[0] = *(const float4*)&Bs[cur][k][tx*4];
      *(float4*)&b[4] = *(const float4*)&Bs[cur][k][tx*4 + 64];
      #pragma unroll
      for (int i = 0; i < 8; ++i)
        #pragma unroll
        for (int j = 0; j < 8; ++j)
          acc[i][j] = fmaf(a[i], b[j], acc[i][j]);
    }
    __syncthreads();
  }
  float bv[8];
  #pragma unroll
  for (int j = 0; j < 8; ++j) bv[j] = bias[bn + (j >> 2) * 64 + tx*4 + (j & 3)];
  #pragma unroll
  for (int i = 0; i < 8; ++i) {
    const int row = bm + (i >> 2) * 64 + ty*4 + (i & 3);
    ushort_t hi[8], lo[8];
    #pragma unroll
    for (int j = 0; j < 8; ++j) {
      const float o = acc[i][j] + bv[j];
      hi[j] = f2b(o);
      lo[j] = f2b(o - b2f(hi[j]));
    }
    ushort_t* dh = Chi + (size_t)row * 512 + bn;
    ushort_t* dl = Clo + (size_t)row * 512 + bn;
    *(uint2*)(dh + tx*4)      = *(const uint2*)&hi[0];
    *(uint2*)(dh + tx*4 + 64) = *(const uint2*)&hi[4];
    *(uint2*)(dl + tx*4)      = *(const uint2*)&lo[0];
    *(uint2*)(dl + tx*4 + 64) = *(const uint2*)&lo[4];
  }
#undef QK_LOAD
#undef QK_STORE
}

// ---- bf16 MFMA GEMM: C[M,512] = A_bf16 @ W + bias, W transposed (Wt[n][k]) ----
__global__ __launch_bounds__(256, 2) void gemm_mfma(
    const ushort_t* __restrict__ A, const ushort_t* __restrict__ Wt,
    const float* __restrict__ bias, float* __restrict__ Cf,
    ushort_t* __restrict__ Cb, int out_bf16)
{
  __shared__ __align__(16) char Al[16384];
  __shared__ __align__(16) char Bl[16384];
  const int bm = blockIdx.x * 128, bn = blockIdx.y * 128;
  const int tid = threadIdx.x, w = tid >> 6, l = tid & 63;
  const int m = l & 15, gq = l >> 4;
  f32x4 acc[2][8] = {};
  for (int k0 = 0; k0 < 512; k0 += 64) {
    const int r = tid >> 1, q = tid & 1;
    const ushort_t* srcA = A  + (size_t)(bm + r) * 512 + k0 + q * 32;
    const ushort_t* srcB = Wt + (size_t)(bn + r) * 512 + k0 + q * 32;
    #pragma unroll
    for (int i = 0; i < 4; ++i) {
      *(uint4*)(Al + ((r * 128 + q * 64 + i * 16) ^ ((r & 7) << 4))) = *(const uint4*)(srcA + i * 8);
      *(uint4*)(Bl + ((r * 128 + q * 64 + i * 16) ^ ((r & 7) << 4))) = *(const uint4*)(srcB + i * 8);
    }
    __syncthreads();
    #pragma unroll
    for (int ks = 0; ks < 2; ++ks) {
      short8 bfr[8];
      #pragma unroll
      for (int tj = 0; tj < 8; ++tj) {
        const int brow = tj * 16 + m;
        bfr[tj] = *(const short8*)(Bl + ((brow * 128 + ks * 64 + gq * 16) ^ ((brow & 7) << 4)));
      }
      #pragma unroll
      for (int ti = 0; ti < 2; ++ti) {
        const int arow = w * 32 + ti * 16 + m;
        const short8 af = *(const short8*)(Al + ((arow * 128 + ks * 64 + gq * 16) ^ ((arow & 7) << 4)));
        #pragma unroll
        for (int tj = 0; tj < 8; ++tj)
          acc[ti][tj] = __builtin_amdgcn_mfma_f32_16x16x32_bf16(af, bfr[tj], acc[ti][tj], 0, 0, 0);
      }
    }
    __syncthreads();
  }
  #pragma unroll
  for (int ti = 0; ti < 2; ++ti)
    #pragma unroll
    for (int tj = 0; tj < 8; ++tj) {
      const int col = bn + tj * 16 + m;
      const float bvv = bias[col];
      #pragma unroll
      for (int r2 = 0; r2 < 4; ++r2) {
        const int row = bm + w * 32 + ti * 16 + gq * 4 + r2;
        const float oo = acc[ti][tj][r2] + bvv;
        if (out_bf16) Cb[(size_t)row * 512 + col] = f2b(oo);
        else          Cf[(size_t)row * 512 + col] = oo;
      }
    }
}

// ---- rot = (qk_hi+qk_lo) @ (R_hi+R_lo)^T via 4 MFMA products, fp32 out ----
__global__ __launch_bounds__(256, 2) void rot_split_mfma(
    const ushort_t* __restrict__ Ah, const ushort_t* __restrict__ Al,
    const ushort_t* __restrict__ Bh, const ushort_t* __restrict__ Bl,
    float* __restrict__ rot)
{
  __shared__ __align__(16) char AH[16384], AL[16384], BH[16384], BL[16384];
  const int bm = blockIdx.x * 128, bn = blockIdx.y * 128;
  const int tid = threadIdx.x, w = tid >> 6, l = tid & 63;
  const int m = l & 15, gq = l >> 4;
  f32x4 acc[2][8] = {};
  for (int k0 = 0; k0 < 512; k0 += 64) {
    const int r = tid >> 1, q = tid & 1;
    const size_t offA = (size_t)(bm + r) * 512 + k0 + q * 32;
    const size_t offB = (size_t)(bn + r) * 512 + k0 + q * 32;
    #pragma unroll
    for (int i = 0; i < 4; ++i) {
      const int dst = (r * 128 + q * 64 + i * 16) ^ ((r & 7) << 4);
      *(uint4*)(AH + dst) = *(const uint4*)(Ah + offA + i * 8);
      *(uint4*)(AL + dst) = *(const uint4*)(Al + offA + i * 8);
      *(uint4*)(BH + dst) = *(const uint4*)(Bh + offB + i * 8);
      *(uint4*)(BL + dst) = *(const uint4*)(Bl + offB + i * 8);
    }
    __syncthreads();
    #pragma unroll
    for (int ks = 0; ks < 2; ++ks) {
      short8 bh8[8], bl8[8];
      #pragma unroll
      for (int tj = 0; tj < 8; ++tj) {
        const int ba = ((tj * 16 + m) * 128 + ks * 64 + gq * 16) ^ (((tj * 16 + m) & 7) << 4);
        bh8[tj] = *(const short8*)(BH + ba);
        bl8[tj] = *(const short8*)(BL + ba);
      }
      #pragma unroll
      for (int ti = 0; ti < 2; ++ti) {
        const int arow = w * 32 + ti * 16 + m;
        const int aa = (arow * 128 + ks * 64 + gq * 16) ^ ((arow & 7) << 4);
        const short8 ah8 = *(const short8*)(AH + aa);
        const short8 al8 = *(const short8*)(AL + aa);
        #pragma unroll
        for (int tj = 0; tj < 8; ++tj) {
          acc[ti][tj] = __builtin_amdgcn_mfma_f32_16x16x32_bf16(ah8, bh8[tj], acc[ti][tj], 0, 0, 0);
          acc[ti][tj] = __builtin_amdgcn_mfma_f32_16x16x32_bf16(ah8, bl8[tj], acc[ti][tj], 0, 0, 0);
          acc[ti][tj] = __builtin_amdgcn_mfma_f32_16x16x32_bf16(al8, bh8[tj], acc[ti][tj], 0, 0, 0);
          acc[ti][tj] = __builtin_amdgcn_mfma_f32_16x16x32_bf16(al8, bl8[tj], acc[ti][tj], 0, 0, 0);
        }
      }
    }
    __syncthreads();
  }
  #pragma unroll
  for (int ti = 0; ti < 2; ++ti)
    #pragma unroll
    for (int tj = 0; tj < 8; ++tj)
      #pragma unroll
      for (int r2 = 0; r2 < 4; ++r2) {
        const int row = bm + w * 32 + ti * 16 + gq * 4 + r2;
        const int col = bn + tj * 16 + m;
        rot[(size_t)row * 256 + col] = acc[ti][tj][r2];
      }
}

// ---- transpose + bf16 cvt: Wt[n][k] = bf16(W[k][n]), 512x512 ----
__global__ __launch_bounds__(256) void transpose_cvt(
    const float* __restrict__ W, ushort_t* __restrict__ Wt)
{
  __shared__ float t[32][33];
  const int bx = blockIdx.x * 32, by = blockIdx.y * 32;
  const int tx = threadIdx.x & 31, ty = threadIdx.x >> 5;
  #pragma unroll
  for (int j = 0; j < 4; ++j)
    t[ty + j*8][tx] = W[(size_t)(by + ty + j*8) * 512 + bx + tx];
  __syncthreads();
  #pragma unroll
  for (int j = 0; j < 4; ++j)
    Wt[(size_t)(bx + ty + j*8) * 512 + by + tx] = f2b(t[tx][ty + j*8]);
}

// ---- transpose + hi/lo split: R[512][256] -> Th/Tl[256][512] bf16 ----
__global__ __launch_bounds__(256) void transpose_split(
    const float* __restrict__ R, ushort_t* __restrict__ Th, ushort_t* __restrict__ Tl)
{
  __shared__ float t[32][33];
  const int bx = blockIdx.x * 32, by = blockIdx.y * 32;   // bx: cols(256), by: rows(512)
  const int tx = threadIdx.x & 31, ty = threadIdx.x >> 5;
  #pragma unroll
  for (int j = 0; j < 4; ++j)
    t[ty + j*8][tx] = R[(size_t)(by + ty + j*8) * 256 + bx + tx];
  __syncthreads();
  #pragma unroll
  for (int j = 0; j < 4; ++j) {
    const float v = t[tx][ty + j*8];
    const ushort_t hi = f2b(v);
    Th[(size_t)(bx + ty + j*8) * 512 + by + tx] = hi;
    Tl[(size_t)(bx + ty + j*8) * 512 + by + tx] = f2b(v - b2f(hi));
  }
}

// ---- argmax over [rot,-rot] + top2 margin; marginal pairs appended to mlist ----
__global__ __launch_bounds__(256) void argmax_margin(
    const float* __restrict__ rot, int* __restrict__ buckets,
    int* __restrict__ mlist, int* __restrict__ mcount, float tau)
{
  const int tok = blockIdx.x;
  const int j = threadIdx.x;             // j = h*32 + i
  const float r = rot[(size_t)tok * 256 + j];
  float m1, m2; int i1;
  if (r >= 0.f) { m1 = r;  i1 = j & 31;        m2 = -r; }
  else          { m1 = -r; i1 = (j & 31) + 32; m2 = r;  }
  #pragma unroll
  for (int off = 16; off; off >>= 1) {
    const float om1 = __shfl_xor(m1, off);
    const int   oi1 = __shfl_xor(i1, off);
    const float om2 = __shfl_xor(m2, off);
    float loser;
    if (om1 > m1 || (om1 == m1 && oi1 < i1)) { loser = m1; m1 = om1; i1 = oi1; }
    else loser = om1;
    m2 = fmaxf(fmaxf(m2, om2), loser);
  }
  if ((j & 31) == 0) {
    const int h = j >> 5, b = tok >> 12, t = tok & 4095;
    buckets[((b << 3) + h) * 4096 + t] = i1;
    if (m1 - m2 < tau) {
      const int k = atomicAdd(mcount, 1);
      mlist[k] = (((b << 3) + h) << 12) | t;
    }
  }
}

// ---- exact np-chain fallback for marginal (b,h,t) pairs ----
__global__ __launch_bounds__(512) void bucket_fallback(
    const float* __restrict__ x, const float* __restrict__ w_qk,
    const float* __restrict__ b_qk, const float* __restrict__ R,
    const int* __restrict__ mlist, const int* __restrict__ mcount,
    int* __restrict__ buckets)
{
  __shared__ float qkrow[512];
  const int n = mcount[0];
  for (int ii = blockIdx.x; ii < n; ii += gridDim.x) {
    const int mm = mlist[ii];
    const int bh = mm >> 12, t = mm & 4095;
    const int b = bh >> 3, h = bh & 7;
    const float* xr = x + ((size_t)b * 4096 + t) * 512;
    {
      const int c = threadIdx.x;
      float a0 = 0.f;
      for (int f = 0; f < 512; ++f) a0 = fmaf(xr[f], w_qk[(size_t)f * 512 + c], a0);
      qkrow[c] = a0 + b_qk[c];
    }
    __syncthreads();
    if (threadIdx.x < 32) {
      const int col = h * 32 + threadIdx.x;
      float a0 = 0.f;
      for (int f = 0; f < 512; ++f) a0 = fmaf(qkrow[f], R[(size_t)f * 256 + col], a0);
      float m1; int i1;
      if (a0 >= 0.f) { m1 = a0;  i1 = threadIdx.x; }
      else           { m1 = -a0; i1 = threadIdx.x + 32; }
      #pragma unroll
      for (int off = 16; off; off >>= 1) {
        const float om = __shfl_xor(m1, off);
        const int   oi = __shfl_xor(i1, off);
        if (om > m1 || (om == m1 && oi < i1)) { m1 = om; i1 = oi; }
      }
      if (threadIdx.x == 0) buckets[(size_t)bh * 4096 + t] = i1;
    }
    __syncthreads();
  }
}

// -------- stable counting sort per (b,h): tokens by (bucket, t) --------
__global__ __launch_bounds__(256) void sort_kernel(
    const int* __restrict__ buckets, int* __restrict__ st)
{
  __shared__ int bk_lds[4096];
  __shared__ int cnt[4][64];
  __shared__ int startq[4][64];
  const int tid = threadIdx.x;
  const int base = blockIdx.x * 4096;     // blockIdx = b*8+h
  for (int t = tid; t < 4096; t += 256) bk_lds[t] = buckets[base + t];
  __syncthreads();
  const int wave = tid >> 6, lane = tid & 63;
  const int q0 = wave * 1024;
  int c = 0;
  for (int t = 0; t < 1024; ++t) c += (bk_lds[q0 + t] == lane);
  cnt[wave][lane] = c;
  __syncthreads();
  if (tid < 64) {
    const int c0 = cnt[0][tid], c1 = cnt[1][tid], c2 = cnt[2][tid], c3 = cnt[3][tid];
    const int tot = c0 + c1 + c2 + c3;
    int ex = tot;
    #pragma unroll
    for (int off = 1; off < 64; off <<= 1) {
      const int nn = __shfl_up(ex, off);
      if (lane >= off) ex += nn;
    }
    const int bucket_start = ex - tot;
    startq[0][tid] = bucket_start;
    startq[1][tid] = bucket_start + c0;
    startq[2][tid] = bucket_start + c0 + c1;
    startq[3][tid] = bucket_start + c0 + c1 + c2;
  }
  __syncthreads();
  int cur = startq[wave][lane];
  for (int t = 0; t < 1024; ++t) {
    if (bk_lds[q0 + t] == lane) { st[base + cur] = q0 + t; cur++; }
  }
}

// -------- scale[token] = D^-0.5 / max(||qk_row||, 1e-12), from hi+lo --------
__global__ __launch_bounds__(256) void scale_kernel(
    const ushort_t* __restrict__ qh, const ushort_t* __restrict__ ql,
    float* __restrict__ scale)
{
  const int wave = threadIdx.x >> 6, lane = threadIdx.x & 63;
  const int tok = blockIdx.x * 4 + wave;
  const uint4 H = *(const uint4*)(qh + (size_t)tok * 512 + lane * 8);
  const uint4 L = *(const uint4*)(ql + (size_t)tok * 512 + lane * 8);
  const unsigned* hp = (const unsigned*)&H;
  const unsigned* lp = (const unsigned*)&L;
  float s = 0.f;
  #pragma unroll
  for (int e = 0; e < 4; ++e) {
    const float v0 = b2f(hp[e] & 0xffffu) + b2f(lp[e] & 0xffffu);
    const float v1 = b2f(hp[e] >> 16)     + b2f(lp[e] >> 16);
    s += v0 * v0 + v1 * v1;
  }
  #pragma unroll
  for (int off = 32; off; off >>= 1) s += __shfl_down(s, off);
  if (lane == 0) {
    const float nn = fmaxf(sqrtf(s), 1e-12f);
    scale[tok] = 0.044194173824159216f / nn;   // 512^-0.5 / norm
  }
}

// -------- MFMA chunked attention (same structure as round 4/5) --------
__global__ __launch_bounds__(256, 2) void attn_mfma(
    const ushort_t* __restrict__ qk_b, const ushort_t* __restrict__ v_b,
    const float* __restrict__ scale, const int* __restrict__ st,
    ushort_t* __restrict__ so, int g, int hbase)
{
  __shared__ __align__(16) char Q[32768];
  __shared__ __align__(16) char VT[32768];
  __shared__ __align__(16) char P[8192];
  __shared__ int   stt[64];
  __shared__ float scl[64];

  const int blk = blockIdx.x;
  const int cpg = g * 64;
  const int b = blk / cpg, rem = blk % cpg;
  const int hl = rem >> 6, c = rem & 63;
  const int tid = threadIdx.x, w = tid >> 6, l = tid & 63;
  const int m = l & 15, gq = l >> 4;

  if (tid < 64) {
    const int s = st[(size_t)((b * 8 + hbase + hl) * 4096) + c * 64 + tid];
    stt[tid] = s;
    scl[tid] = scale[b * 4096 + s];
  }
  __syncthreads();

  const size_t qkbase = (size_t)b * 4096;
  f32x4 accS[4] = {};

  for (int half = 0; half < 2; ++half) {
    #pragma unroll
    for (int it = 0; it < 8; ++it) {
      const int blk16 = it * 256 + tid;
      const int row = blk16 >> 5, u = blk16 & 31;
      const uint4 dat = *(const uint4*)(qk_b + (qkbase + stt[row]) * 512 + half * 256 + u * 8);
      *(uint4*)(Q + ((row * 512 + u * 16) ^ ((row & 7) << 4))) = dat;
    }
    __syncthreads();
    #pragma unroll
    for (int kf = 0; kf < 8; ++kf) {
      const int arow = w * 16 + m;
      const short8 af = *(const short8*)(Q + ((arow * 512 + kf * 64 + gq * 16) ^ ((arow & 7) << 4)));
      #pragma unroll
      for (int jt = 0; jt < 4; ++jt) {
        const int brow = jt * 16 + m;
        const short8 bf = *(const short8*)(Q + ((brow * 512 + kf * 64 + gq * 16) ^ ((brow & 7) << 4)));
        accS[jt] = __builtin_amdgcn_mfma_f32_16x16x32_bf16(af, bf, accS[jt], 0, 0, 0);
      }
    }
    __syncthreads();
  }

  #pragma unroll
  for (int jt = 0; jt < 4; ++jt)
    #pragma unroll
    for (int r = 0; r < 4; ++r) {
      const int i = w * 16 + gq * 4 + r;
      const int j = jt * 16 + m;
      *(ushort_t*)(P + ((i * 128 + j * 2) ^ ((i & 7) << 4))) = f2b(accS[jt][r] * scl[j]);
    }

  const size_t sobase = (size_t)(b * g + hl) * 4096;
  for (int half = 0; half < 2; ++half) {
    #pragma unroll
    for (int it = 0; it < 8; ++it) {
      const int blk16 = it * 256 + tid;
      const int j = blk16 >> 5, u = blk16 & 31;
      const uint4 dat = *(const uint4*)(v_b + (qkbase + stt[j]) * 512 + half * 256 + u * 8);
      const ushort_t* e = (const ushort_t*)&dat;
      #pragma unroll
      for (int ee = 0; ee < 8; ++ee) {
        const int d = u * 8 + ee;
        *(ushort_t*)(VT + ((d * 128 + j * 2) ^ (((d ^ (d >> 3)) & 7) << 4))) = e[ee];
      }
    }
    __syncthreads();

    short8 ap[2];
    #pragma unroll
    for (int kf = 0; kf < 2; ++kf) {
      const int i = w * 16 + m;
      ap[kf] = *(const short8*)(P + ((i * 128 + kf * 64 + gq * 16) ^ ((i & 7) << 4)));
    }
    f32x4 accO[16] = {};
    #pragma unroll
    for (int dt = 0; dt < 16; ++dt) {
      #pragma unroll
      for (int kf = 0; kf < 2; ++kf) {
        const int d = dt * 16 + m;
        const short8 bv = *(const short8*)(VT + ((d * 128 + kf * 64 + gq * 16) ^ (((d ^ (d >> 3)) & 7) << 4)));
        accO[dt] = __builtin_amdgcn_mfma_f32_16x16x32_bf16(ap[kf], bv, accO[dt], 0, 0, 0);
      }
    }
    __syncthreads();

    #pragma unroll
    for (int dt = 0; dt < 16; ++dt)
      #pragma unroll
      for (int r = 0; r < 4; ++r) {
        const int i = w * 16 + gq * 4 + r;
        const int dcol = dt * 16 + m;
        *(ushort_t*)(Q + ((i * 512 + dcol * 2) ^ ((i & 7) << 4))) = f2b(accO[dt][r]);
      }
    __syncthreads();

    #pragma unroll
    for (int it = 0; it < 8; ++it) {
      const int blk16 = it * 256 + tid;
      const int row = blk16 >> 5, u = blk16 & 31;
      const uint4 dat = *(const uint4*)(Q + ((row * 512 + u * 16) ^ ((row & 7) << 4)));
      *(uint4*)(so + (sobase + stt[row]) * 512 + half * 256 + u * 8) = dat;
    }
  }
}

// -------- gather: o_b[tok][:] (+)= sum_{hl<g} so[(b*g+hl)*4096 + t][:], bf16 --------
__global__ __launch_bounds__(256) void gather_kernel(
    const ushort_t* __restrict__ so, ushort_t* __restrict__ o_b, int g, int first)
{
  const int tok = blockIdx.x;
  const int b = tok >> 12, t = tok & 4095;
  const int d0 = threadIdx.x * 2;
  ushort_t* dst = o_b + (size_t)tok * 512 + d0;
  float ax = 0.f, ay = 0.f;
  if (!first) {
    const unsigned u = *(const unsigned*)dst;
    ax = b2f(u & 0xffffu); ay = b2f(u >> 16);
  }
  const size_t stride = (size_t)4096 * 512;
  const ushort_t* src = so + ((size_t)(b * g) * 4096 + t) * 512 + d0;
  for (int hlp = 0; hlp < g; ++hlp) {
    const unsigned u = *(const unsigned*)src;
    ax += b2f(u & 0xffffu);
    ay += b2f(u >> 16);
    src += stride;
  }
  *(unsigned*)dst = ((unsigned)f2b(ay) << 16) | (unsigned)f2b(ax);
}

extern "C" void kernel_launch(void* const* d_in, const int* in_sizes, int n_in,
                              void* d_out, int out_size, void* d_ws, size_t ws_size,
                              hipStream_t stream) {
  const float* x         = (const float*)d_in[0];
  const float* rotations = (const float*)d_in[1];
  const float* w_qk      = (const float*)d_in[2];
  const float* b_qk      = (const float*)d_in[3];
  const float* w_v       = (const float*)d_in[4];
  const float* b_v       = (const float*)d_in[5];
  const float* w_out     = (const float*)d_in[6];
  const float* b_out     = (const float*)d_in[7];
  float* out = (float*)d_out;
  char* ws = (char*)d_ws;

  ushort_t* x_b     = (ushort_t*)(ws);                  // 16.78 MB
  ushort_t* qk_hi   = (ushort_t*)(ws + 16777216);       // 16.78 MB (== qk_b)
  ushort_t* qk_lo   = (ushort_t*)(ws + 33554432);       // 16.78 MB
  ushort_t* v_b     = (ushort_t*)(ws + 50331648);       // 16.78 MB
  float*    rot     = (float*)(ws + 67108864);          // 16.78 MB (dead after fallback)
  ushort_t* o_b     = (ushort_t*)(ws + 67108864);       // alias: lives after gather
  ushort_t* wvT     = (ushort_t*)(ws + 83886080);       // 512 KB
  ushort_t* woT     = (ushort_t*)(ws + 84410368);       // 512 KB
  ushort_t* Rth     = (ushort_t*)(ws + 84934656);       // 256 KB
  ushort_t* Rtl     = (ushort_t*)(ws + 85196800);       // 256 KB
  float*    scale   = (float*)(ws + 85458944);          // 64 KB
  int*      buckets = (int*)(ws + 85524480);            // 512 KB
  int*      st      = (int*)(ws + 86048768);            // 512 KB
  int*      mlist   = (int*)(ws + 86573056);            // 512 KB (capacity 131072: never overflows)
  int*      mcount  = (int*)(ws + 87097344);            // 4 KB
  ushort_t* so      = (ushort_t*)(ws + 87101440);       // g * 16.78 MB
  const size_t so_off = 87101440;

  int g = 1;
  for (int cand = 8; cand >= 1; cand >>= 1)
    if (so_off + (size_t)cand * 16777216ull <= ws_size) { g = cand; break; }

  const dim3 blk256(256);
  hipLaunchKernelGGL(gemm_qk_f32, dim3(128, 4), blk256, 0, stream,
                     x, w_qk, b_qk, qk_hi, qk_lo, x_b /* y==0 handled below */);
  // NOTE: x_b written only by blockIdx.y==0 blocks — enforced by pointer nulling trick:
  // (we pass x_b; kernel writes for all y would race identically-valued data, so instead
  //  the kernel checks nothing — to keep determinism, all y-blocks write identical bytes.)
  hipLaunchKernelGGL(transpose_cvt, dim3(16, 16), blk256, 0, stream, w_v, wvT);
  hipLaunchKernelGGL(transpose_cvt, dim3(16, 16), blk256, 0, stream, w_out, woT);
  hipLaunchKernelGGL(transpose_split, dim3(8, 16), blk256, 0, stream, rotations, Rth, Rtl);
  hipLaunchKernelGGL(gemm_mfma, dim3(128, 4), blk256, 0, stream, x_b, wvT, b_v, (float*)0, v_b, 1);
  hipLaunchKernelGGL(rot_split_mfma, dim3(128, 2), blk256, 0, stream, qk_hi, qk_lo, Rth, Rtl, rot);
  hipMemsetAsync(mcount, 0, 4, stream);
  hipLaunchKernelGGL(argmax_margin, dim3(16384), blk256, 0, stream, rot, buckets, mlist, mcount, 5e-3f);
  hipLaunchKernelGGL(bucket_fallback, dim3(256), dim3(512), 0, stream,
                     x, w_qk, b_qk, rotations, mlist, mcount, buckets);
  hipLaunchKernelGGL(sort_kernel, dim3(32), blk256, 0, stream, buckets, st);
  hipLaunchKernelGGL(scale_kernel, dim3(4096), blk256, 0, stream, qk_hi, qk_lo, scale);

  const int passes = 8 / g;
  for (int p = 0; p < passes; ++p) {
    const int hbase = p * g;
    hipLaunchKernelGGL(attn_mfma, dim3(4 * g * 64), blk256, 0, stream,
                       qk_hi, v_b, scale, st, so, g, hbase);
    hipLaunchKernelGGL(gather_kernel, dim3(16384), blk256, 0, stream,
                       so, o_b, g, (p == 0) ? 1 : 0);
  }

  hipLaunchKernelGGL(gemm_mfma, dim3(128, 4), blk256, 0, stream, o_b, woT, b_out, out, (ushort_t*)0, 0);
}

// Round 7
// 347.976 us; speedup vs baseline: 6.8837x; 1.1868x over previous
//
#include <hip/hip_runtime.h>

// LSH attention, B=4, T=4096, D=512, H=8 hashes, 64 buckets/hash, bucket size 64.
// Round 7: eliminate the bit-exact fp32 qk GEMM entirely.
//   buckets: rot = x @ (w_qk@R) via 3-product split-bf16 MFMA + margin test
//            + exact np-chain fallback for marginal (token,hash) pairs.
//   attention: qk via 2-product split-bf16 MFMA (continuous path, bf16-level).
//   v / out GEMMs: single-product bf16 MFMA (unchanged).

typedef __attribute__((ext_vector_type(8))) short short8;
typedef __attribute__((ext_vector_type(4))) float f32x4;
typedef unsigned short ushort_t;

__device__ __forceinline__ ushort_t f2b(float f) {
  union { float f; unsigned u; } x; x.f = f;
  unsigned r = x.u + 0x7fffu + ((x.u >> 16) & 1u);
  return (ushort_t)(r >> 16);
}
__device__ __forceinline__ float b2f(unsigned b) {
  union { unsigned u; float f; } x; x.u = b << 16;
  return x.f;
}

// -------- split x into bf16 hi/lo (8 elems/thread) --------
__global__ __launch_bounds__(256) void split_x(
    const float* __restrict__ src, ushort_t* __restrict__ xh,
    ushort_t* __restrict__ xl, int n8)
{
  const int i = blockIdx.x * 256 + threadIdx.x;
  if (i >= n8) return;
  const float4 a = *(const float4*)(src + (size_t)i * 8);
  const float4 c = *(const float4*)(src + (size_t)i * 8 + 4);
  float v[8] = { a.x, a.y, a.z, a.w, c.x, c.y, c.z, c.w };
  ushort_t hi[8], lo[8];
  #pragma unroll
  for (int k = 0; k < 8; ++k) {
    hi[k] = f2b(v[k]);
    lo[k] = f2b(v[k] - b2f(hi[k]));
  }
  *(uint4*)(xh + (size_t)i * 8) = *(const uint4*)hi;
  *(uint4*)(xl + (size_t)i * 8) = *(const uint4*)lo;
}

// ---- transpose + bf16 cvt: Wt[n][k] = bf16(W[k][n]), 512x512 ----
__global__ __launch_bounds__(256) void transpose_cvt(
    const float* __restrict__ W, ushort_t* __restrict__ Wt)
{
  __shared__ float t[32][33];
  const int bx = blockIdx.x * 32, by = blockIdx.y * 32;
  const int tx = threadIdx.x & 31, ty = threadIdx.x >> 5;
  #pragma unroll
  for (int j = 0; j < 4; ++j)
    t[ty + j*8][tx] = W[(size_t)(by + ty + j*8) * 512 + bx + tx];
  __syncthreads();
  #pragma unroll
  for (int j = 0; j < 4; ++j)
    Wt[(size_t)(bx + ty + j*8) * 512 + by + tx] = f2b(t[tx][ty + j*8]);
}

// ---- W2T split: W2Th/W2Tl[j][e] = split(sum_f w_qk[e][f] R[f][j]); b2 = b_qk @ R ----
__global__ __launch_bounds__(256) void w2_split(
    const float* __restrict__ w_qk, const float* __restrict__ b_qk,
    const float* __restrict__ R,
    ushort_t* __restrict__ W2Th, ushort_t* __restrict__ W2Tl, float* __restrict__ b2)
{
  __shared__ float wrow[512];
  const int e = blockIdx.x, j = threadIdx.x;    // j in [0,256)
  const float* src = (e < 512) ? (w_qk + (size_t)e * 512) : b_qk;
  wrow[j]       = src[j];
  wrow[j + 256] = src[j + 256];
  __syncthreads();
  float acc = 0.f;
  for (int f = 0; f < 512; ++f)
    acc = fmaf(wrow[f], R[(size_t)f * 256 + j], acc);
  if (e < 512) {
    const ushort_t hi = f2b(acc);
    W2Th[(size_t)j * 512 + e] = hi;
    W2Tl[(size_t)j * 512 + e] = f2b(acc - b2f(hi));
  } else {
    b2[j] = acc;
  }
}

// ---- bf16 MFMA GEMM (1 product): C = A @ Wt^T + bias ----
__global__ __launch_bounds__(256, 2) void gemm_mfma(
    const ushort_t* __restrict__ A, const ushort_t* __restrict__ Wt,
    const float* __restrict__ bias, float* __restrict__ Cf,
    ushort_t* __restrict__ Cb, int out_bf16)
{
  __shared__ __align__(16) char Al[16384];
  __shared__ __align__(16) char Bl[16384];
  const int bm = blockIdx.x * 128, bn = blockIdx.y * 128;
  const int tid = threadIdx.x, w = tid >> 6, l = tid & 63;
  const int m = l & 15, gq = l >> 4;
  f32x4 acc[2][8] = {};
  for (int k0 = 0; k0 < 512; k0 += 64) {
    const int r = tid >> 1, q = tid & 1;
    const ushort_t* srcA = A  + (size_t)(bm + r) * 512 + k0 + q * 32;
    const ushort_t* srcB = Wt + (size_t)(bn + r) * 512 + k0 + q * 32;
    #pragma unroll
    for (int i = 0; i < 4; ++i) {
      *(uint4*)(Al + ((r * 128 + q * 64 + i * 16) ^ ((r & 7) << 4))) = *(const uint4*)(srcA + i * 8);
      *(uint4*)(Bl + ((r * 128 + q * 64 + i * 16) ^ ((r & 7) << 4))) = *(const uint4*)(srcB + i * 8);
    }
    __syncthreads();
    #pragma unroll
    for (int ks = 0; ks < 2; ++ks) {
      short8 bfr[8];
      #pragma unroll
      for (int tj = 0; tj < 8; ++tj) {
        const int brow = tj * 16 + m;
        bfr[tj] = *(const short8*)(Bl + ((brow * 128 + ks * 64 + gq * 16) ^ ((brow & 7) << 4)));
      }
      #pragma unroll
      for (int ti = 0; ti < 2; ++ti) {
        const int arow = w * 32 + ti * 16 + m;
        const short8 af = *(const short8*)(Al + ((arow * 128 + ks * 64 + gq * 16) ^ ((arow & 7) << 4)));
        #pragma unroll
        for (int tj = 0; tj < 8; ++tj)
          acc[ti][tj] = __builtin_amdgcn_mfma_f32_16x16x32_bf16(af, bfr[tj], acc[ti][tj], 0, 0, 0);
      }
    }
    __syncthreads();
  }
  #pragma unroll
  for (int ti = 0; ti < 2; ++ti)
    #pragma unroll
    for (int tj = 0; tj < 8; ++tj) {
      const int col = bn + tj * 16 + m;
      const float bvv = bias[col];
      #pragma unroll
      for (int r2 = 0; r2 < 4; ++r2) {
        const int row = bm + w * 32 + ti * 16 + gq * 4 + r2;
        const float oo = acc[ti][tj][r2] + bvv;
        if (out_bf16) Cb[(size_t)row * 512 + col] = f2b(oo);
        else          Cf[(size_t)row * 512 + col] = oo;
      }
    }
}

// ---- bf16 MFMA GEMM (2 A-products): C = (Ah+Al) @ Wt^T + bias -> bf16 ----
__global__ __launch_bounds__(256, 2) void gemm_mfma_x2(
    const ushort_t* __restrict__ Ah, const ushort_t* __restrict__ Al,
    const ushort_t* __restrict__ Wt, const float* __restrict__ bias,
    ushort_t* __restrict__ Cb)
{
  __shared__ __align__(16) char AH[16384], AL[16384], BH[16384];
  const int bm = blockIdx.x * 128, bn = blockIdx.y * 128;
  const int tid = threadIdx.x, w = tid >> 6, l = tid & 63;
  const int m = l & 15, gq = l >> 4;
  f32x4 acc[2][8] = {};
  for (int k0 = 0; k0 < 512; k0 += 64) {
    const int r = tid >> 1, q = tid & 1;
    const size_t offA = (size_t)(bm + r) * 512 + k0 + q * 32;
    const size_t offB = (size_t)(bn + r) * 512 + k0 + q * 32;
    #pragma unroll
    for (int i = 0; i < 4; ++i) {
      const int dst = (r * 128 + q * 64 + i * 16) ^ ((r & 7) << 4);
      *(uint4*)(AH + dst) = *(const uint4*)(Ah + offA + i * 8);
      *(uint4*)(AL + dst) = *(const uint4*)(Al + offA + i * 8);
      *(uint4*)(BH + dst) = *(const uint4*)(Wt + offB + i * 8);
    }
    __syncthreads();
    #pragma unroll
    for (int ks = 0; ks < 2; ++ks) {
      short8 bfr[8];
      #pragma unroll
      for (int tj = 0; tj < 8; ++tj) {
        const int brow = tj * 16 + m;
        bfr[tj] = *(const short8*)(BH + ((brow * 128 + ks * 64 + gq * 16) ^ ((brow & 7) << 4)));
      }
      #pragma unroll
      for (int ti = 0; ti < 2; ++ti) {
        const int arow = w * 32 + ti * 16 + m;
        const int aa = (arow * 128 + ks * 64 + gq * 16) ^ ((arow & 7) << 4);
        const short8 ah8 = *(const short8*)(AH + aa);
        const short8 al8 = *(const short8*)(AL + aa);
        #pragma unroll
        for (int tj = 0; tj < 8; ++tj) {
          acc[ti][tj] = __builtin_amdgcn_mfma_f32_16x16x32_bf16(ah8, bfr[tj], acc[ti][tj], 0, 0, 0);
          acc[ti][tj] = __builtin_amdgcn_mfma_f32_16x16x32_bf16(al8, bfr[tj], acc[ti][tj], 0, 0, 0);
        }
      }
    }
    __syncthreads();
  }
  #pragma unroll
  for (int ti = 0; ti < 2; ++ti)
    #pragma unroll
    for (int tj = 0; tj < 8; ++tj) {
      const int col = bn + tj * 16 + m;
      const float bvv = bias[col];
      #pragma unroll
      for (int r2 = 0; r2 < 4; ++r2) {
        const int row = bm + w * 32 + ti * 16 + gq * 4 + r2;
        Cb[(size_t)row * 512 + col] = f2b(acc[ti][tj][r2] + bvv);
      }
    }
}

// ---- rot = (xh+xl)@(W2h+W2l)^T + b2 via 3 MFMA products (lo*lo dropped), fp32 ----
__global__ __launch_bounds__(256, 2) void rot3_mfma(
    const ushort_t* __restrict__ Ah, const ushort_t* __restrict__ Al,
    const ushort_t* __restrict__ Bh, const ushort_t* __restrict__ Bl,
    const float* __restrict__ b2, float* __restrict__ rot)
{
  __shared__ __align__(16) char AH[16384], AL[16384], BH[16384], BL[16384];
  const int bm = blockIdx.x * 128, bn = blockIdx.y * 128;
  const int tid = threadIdx.x, w = tid >> 6, l = tid & 63;
  const int m = l & 15, gq = l >> 4;
  f32x4 acc[2][8] = {};
  for (int k0 = 0; k0 < 512; k0 += 64) {
    const int r = tid >> 1, q = tid & 1;
    const size_t offA = (size_t)(bm + r) * 512 + k0 + q * 32;
    const size_t offB = (size_t)(bn + r) * 512 + k0 + q * 32;
    #pragma unroll
    for (int i = 0; i < 4; ++i) {
      const int dst = (r * 128 + q * 64 + i * 16) ^ ((r & 7) << 4);
      *(uint4*)(AH + dst) = *(const uint4*)(Ah + offA + i * 8);
      *(uint4*)(AL + dst) = *(const uint4*)(Al + offA + i * 8);
      *(uint4*)(BH + dst) = *(const uint4*)(Bh + offB + i * 8);
      *(uint4*)(BL + dst) = *(const uint4*)(Bl + offB + i * 8);
    }
    __syncthreads();
    #pragma unroll
    for (int ks = 0; ks < 2; ++ks) {
      short8 bh8[8], bl8[8];
      #pragma unroll
      for (int tj = 0; tj < 8; ++tj) {
        const int ba = ((tj * 16 + m) * 128 + ks * 64 + gq * 16) ^ (((tj * 16 + m) & 7) << 4);
        bh8[tj] = *(const short8*)(BH + ba);
        bl8[tj] = *(const short8*)(BL + ba);
      }
      #pragma unroll
      for (int ti = 0; ti < 2; ++ti) {
        const int arow = w * 32 + ti * 16 + m;
        const int aa = (arow * 128 + ks * 64 + gq * 16) ^ ((arow & 7) << 4);
        const short8 ah8 = *(const short8*)(AH + aa);
        const short8 al8 = *(const short8*)(AL + aa);
        #pragma unroll
        for (int tj = 0; tj < 8; ++tj) {
          acc[ti][tj] = __builtin_amdgcn_mfma_f32_16x16x32_bf16(ah8, bh8[tj], acc[ti][tj], 0, 0, 0);
          acc[ti][tj] = __builtin_amdgcn_mfma_f32_16x16x32_bf16(al8, bh8[tj], acc[ti][tj], 0, 0, 0);
          acc[ti][tj] = __builtin_amdgcn_mfma_f32_16x16x32_bf16(ah8, bl8[tj], acc[ti][tj], 0, 0, 0);
        }
      }
    }
    __syncthreads();
  }
  #pragma unroll
  for (int ti = 0; ti < 2; ++ti)
    #pragma unroll
    for (int tj = 0; tj < 8; ++tj) {
      const int col = bn + tj * 16 + m;
      const float bvv = b2[col];
      #pragma unroll
      for (int r2 = 0; r2 < 4; ++r2) {
        const int row = bm + w * 32 + ti * 16 + gq * 4 + r2;
        rot[(size_t)row * 256 + col] = acc[ti][tj][r2] + bvv;
      }
    }
}

// ---- argmax over [rot,-rot] + top2 margin; marginal pairs appended to mlist ----
__global__ __launch_bounds__(256) void argmax_margin(
    const float* __restrict__ rot, int* __restrict__ buckets,
    int* __restrict__ mlist, int* __restrict__ mcount, float tau)
{
  const int tok = blockIdx.x;
  const int j = threadIdx.x;             // j = h*32 + i
  const float r = rot[(size_t)tok * 256 + j];
  float m1, m2; int i1;
  if (r >= 0.f) { m1 = r;  i1 = j & 31;        m2 = -r; }
  else          { m1 = -r; i1 = (j & 31) + 32; m2 = r;  }
  #pragma unroll
  for (int off = 16; off; off >>= 1) {
    const float om1 = __shfl_xor(m1, off);
    const int   oi1 = __shfl_xor(i1, off);
    const float om2 = __shfl_xor(m2, off);
    float loser;
    if (om1 > m1 || (om1 == m1 && oi1 < i1)) { loser = m1; m1 = om1; i1 = oi1; }
    else loser = om1;
    m2 = fmaxf(fmaxf(m2, om2), loser);
  }
  if ((j & 31) == 0) {
    const int h = j >> 5, b = tok >> 12, t = tok & 4095;
    buckets[((b << 3) + h) * 4096 + t] = i1;
    if (m1 - m2 < tau) {
      const int k = atomicAdd(mcount, 1);
      mlist[k] = (((b << 3) + h) << 12) | t;
    }
  }
}

// ---- exact np-chain fallback for marginal (b,h,t) pairs ----
__global__ __launch_bounds__(512) void bucket_fallback(
    const float* __restrict__ x, const float* __restrict__ w_qk,
    const float* __restrict__ b_qk, const float* __restrict__ R,
    const int* __restrict__ mlist, const int* __restrict__ mcount,
    int* __restrict__ buckets)
{
  __shared__ float qkrow[512];
  const int n = mcount[0];
  for (int ii = blockIdx.x; ii < n; ii += gridDim.x) {
    const int mm = mlist[ii];
    const int bh = mm >> 12, t = mm & 4095;
    const int b = bh >> 3, h = bh & 7;
    const float* xr = x + ((size_t)b * 4096 + t) * 512;
    {
      const int c = threadIdx.x;
      float a0 = 0.f;
      for (int f = 0; f < 512; ++f) a0 = fmaf(xr[f], w_qk[(size_t)f * 512 + c], a0);
      qkrow[c] = a0 + b_qk[c];
    }
    __syncthreads();
    if (threadIdx.x < 32) {
      const int col = h * 32 + threadIdx.x;
      float a0 = 0.f;
      for (int f = 0; f < 512; ++f) a0 = fmaf(qkrow[f], R[(size_t)f * 256 + col], a0);
      float m1; int i1;
      if (a0 >= 0.f) { m1 = a0;  i1 = threadIdx.x; }
      else           { m1 = -a0; i1 = threadIdx.x + 32; }
      #pragma unroll
      for (int off = 16; off; off >>= 1) {
        const float om = __shfl_xor(m1, off);
        const int   oi = __shfl_xor(i1, off);
        if (om > m1 || (om == m1 && oi < i1)) { m1 = om; i1 = oi; }
      }
      if (threadIdx.x == 0) buckets[(size_t)bh * 4096 + t] = i1;
    }
    __syncthreads();
  }
}

// -------- stable counting sort per (b,h): tokens by (bucket, t) --------
__global__ __launch_bounds__(256) void sort_kernel(
    const int* __restrict__ buckets, int* __restrict__ st)
{
  __shared__ int bk_lds[4096];
  __shared__ int cnt[4][64];
  __shared__ int startq[4][64];
  const int tid = threadIdx.x;
  const int base = blockIdx.x * 4096;     // blockIdx = b*8+h
  for (int t = tid; t < 4096; t += 256) bk_lds[t] = buckets[base + t];
  __syncthreads();
  const int wave = tid >> 6, lane = tid & 63;
  const int q0 = wave * 1024;
  int c = 0;
  for (int t = 0; t < 1024; ++t) c += (bk_lds[q0 + t] == lane);
  cnt[wave][lane] = c;
  __syncthreads();
  if (tid < 64) {
    const int c0 = cnt[0][tid], c1 = cnt[1][tid], c2 = cnt[2][tid], c3 = cnt[3][tid];
    const int tot = c0 + c1 + c2 + c3;
    int ex = tot;
    #pragma unroll
    for (int off = 1; off < 64; off <<= 1) {
      const int nn = __shfl_up(ex, off);
      if (lane >= off) ex += nn;
    }
    const int bucket_start = ex - tot;
    startq[0][tid] = bucket_start;
    startq[1][tid] = bucket_start + c0;
    startq[2][tid] = bucket_start + c0 + c1;
    startq[3][tid] = bucket_start + c0 + c1 + c2;
  }
  __syncthreads();
  int cur = startq[wave][lane];
  for (int t = 0; t < 1024; ++t) {
    if (bk_lds[q0 + t] == lane) { st[base + cur] = q0 + t; cur++; }
  }
}

// -------- scale[token] = D^-0.5 / max(||qk_hi row||, 1e-12) --------
__global__ __launch_bounds__(256) void scale_kernel(
    const ushort_t* __restrict__ qh, float* __restrict__ scale)
{
  const int wave = threadIdx.x >> 6, lane = threadIdx.x & 63;
  const int tok = blockIdx.x * 4 + wave;
  const uint4 H = *(const uint4*)(qh + (size_t)tok * 512 + lane * 8);
  const unsigned* hp = (const unsigned*)&H;
  float s = 0.f;
  #pragma unroll
  for (int e = 0; e < 4; ++e) {
    const float v0 = b2f(hp[e] & 0xffffu);
    const float v1 = b2f(hp[e] >> 16);
    s += v0 * v0 + v1 * v1;
  }
  #pragma unroll
  for (int off = 32; off; off >>= 1) s += __shfl_down(s, off);
  if (lane == 0) {
    const float nn = fmaxf(sqrtf(s), 1e-12f);
    scale[tok] = 0.044194173824159216f / nn;   // 512^-0.5 / norm
  }
}

// -------- MFMA chunked attention (structure unchanged since round 4) --------
__global__ __launch_bounds__(256, 2) void attn_mfma(
    const ushort_t* __restrict__ qk_b, const ushort_t* __restrict__ v_b,
    const float* __restrict__ scale, const int* __restrict__ st,
    ushort_t* __restrict__ so, int g, int hbase)
{
  __shared__ __align__(16) char Q[32768];
  __shared__ __align__(16) char VT[32768];
  __shared__ __align__(16) char P[8192];
  __shared__ int   stt[64];
  __shared__ float scl[64];

  const int blk = blockIdx.x;
  const int cpg = g * 64;
  const int b = blk / cpg, rem = blk % cpg;
  const int hl = rem >> 6, c = rem & 63;
  const int tid = threadIdx.x, w = tid >> 6, l = tid & 63;
  const int m = l & 15, gq = l >> 4;

  if (tid < 64) {
    const int s = st[(size_t)((b * 8 + hbase + hl) * 4096) + c * 64 + tid];
    stt[tid] = s;
    scl[tid] = scale[b * 4096 + s];
  }
  __syncthreads();

  const size_t qkbase = (size_t)b * 4096;
  f32x4 accS[4] = {};

  for (int half = 0; half < 2; ++half) {
    #pragma unroll
    for (int it = 0; it < 8; ++it) {
      const int blk16 = it * 256 + tid;
      const int row = blk16 >> 5, u = blk16 & 31;
      const uint4 dat = *(const uint4*)(qk_b + (qkbase + stt[row]) * 512 + half * 256 + u * 8);
      *(uint4*)(Q + ((row * 512 + u * 16) ^ ((row & 7) << 4))) = dat;
    }
    __syncthreads();
    #pragma unroll
    for (int kf = 0; kf < 8; ++kf) {
      const int arow = w * 16 + m;
      const short8 af = *(const short8*)(Q + ((arow * 512 + kf * 64 + gq * 16) ^ ((arow & 7) << 4)));
      #pragma unroll
      for (int jt = 0; jt < 4; ++jt) {
        const int brow = jt * 16 + m;
        const short8 bf = *(const short8*)(Q + ((brow * 512 + kf * 64 + gq * 16) ^ ((brow & 7) << 4)));
        accS[jt] = __builtin_amdgcn_mfma_f32_16x16x32_bf16(af, bf, accS[jt], 0, 0, 0);
      }
    }
    __syncthreads();
  }

  #pragma unroll
  for (int jt = 0; jt < 4; ++jt)
    #pragma unroll
    for (int r = 0; r < 4; ++r) {
      const int i = w * 16 + gq * 4 + r;
      const int j = jt * 16 + m;
      *(ushort_t*)(P + ((i * 128 + j * 2) ^ ((i & 7) << 4))) = f2b(accS[jt][r] * scl[j]);
    }

  const size_t sobase = (size_t)(b * g + hl) * 4096;
  for (int half = 0; half < 2; ++half) {
    #pragma unroll
    for (int it = 0; it < 8; ++it) {
      const int blk16 = it * 256 + tid;
      const int j = blk16 >> 5, u = blk16 & 31;
      const uint4 dat = *(const uint4*)(v_b + (qkbase + stt[j]) * 512 + half * 256 + u * 8);
      const ushort_t* e = (const ushort_t*)&dat;
      #pragma unroll
      for (int ee = 0; ee < 8; ++ee) {
        const int d = u * 8 + ee;
        *(ushort_t*)(VT + ((d * 128 + j * 2) ^ (((d ^ (d >> 3)) & 7) << 4))) = e[ee];
      }
    }
    __syncthreads();

    short8 ap[2];
    #pragma unroll
    for (int kf = 0; kf < 2; ++kf) {
      const int i = w * 16 + m;
      ap[kf] = *(const short8*)(P + ((i * 128 + kf * 64 + gq * 16) ^ ((i & 7) << 4)));
    }
    f32x4 accO[16] = {};
    #pragma unroll
    for (int dt = 0; dt < 16; ++dt) {
      #pragma unroll
      for (int kf = 0; kf < 2; ++kf) {
        const int d = dt * 16 + m;
        const short8 bv = *(const short8*)(VT + ((d * 128 + kf * 64 + gq * 16) ^ (((d ^ (d >> 3)) & 7) << 4)));
        accO[dt] = __builtin_amdgcn_mfma_f32_16x16x32_bf16(ap[kf], bv, accO[dt], 0, 0, 0);
      }
    }
    __syncthreads();

    #pragma unroll
    for (int dt = 0; dt < 16; ++dt)
      #pragma unroll
      for (int r = 0; r < 4; ++r) {
        const int i = w * 16 + gq * 4 + r;
        const int dcol = dt * 16 + m;
        *(ushort_t*)(Q + ((i * 512 + dcol * 2) ^ ((i & 7) << 4))) = f2b(accO[dt][r]);
      }
    __syncthreads();

    #pragma unroll
    for (int it = 0; it < 8; ++it) {
      const int blk16 = it * 256 + tid;
      const int row = blk16 >> 5, u = blk16 & 31;
      const uint4 dat = *(const uint4*)(Q + ((row * 512 + u * 16) ^ ((row & 7) << 4)));
      *(uint4*)(so + (sobase + stt[row]) * 512 + half * 256 + u * 8) = dat;
    }
  }
}

// -------- gather: o_b[tok][:] (+)= sum_{hl<g} so[(b*g+hl)*4096 + t][:], bf16 --------
__global__ __launch_bounds__(256) void gather_kernel(
    const ushort_t* __restrict__ so, ushort_t* __restrict__ o_b, int g, int first)
{
  const int tok = blockIdx.x;
  const int b = tok >> 12, t = tok & 4095;
  const int d0 = threadIdx.x * 2;
  ushort_t* dst = o_b + (size_t)tok * 512 + d0;
  float ax = 0.f, ay = 0.f;
  if (!first) {
    const unsigned u = *(const unsigned*)dst;
    ax = b2f(u & 0xffffu); ay = b2f(u >> 16);
  }
  const size_t stride = (size_t)4096 * 512;
  const ushort_t* src = so + ((size_t)(b * g) * 4096 + t) * 512 + d0;
  for (int hlp = 0; hlp < g; ++hlp) {
    const unsigned u = *(const unsigned*)src;
    ax += b2f(u & 0xffffu);
    ay += b2f(u >> 16);
    src += stride;
  }
  *(unsigned*)dst = ((unsigned)f2b(ay) << 16) | (unsigned)f2b(ax);
}

extern "C" void kernel_launch(void* const* d_in, const int* in_sizes, int n_in,
                              void* d_out, int out_size, void* d_ws, size_t ws_size,
                              hipStream_t stream) {
  const float* x         = (const float*)d_in[0];
  const float* rotations = (const float*)d_in[1];
  const float* w_qk      = (const float*)d_in[2];
  const float* b_qk      = (const float*)d_in[3];
  const float* w_v       = (const float*)d_in[4];
  const float* b_v       = (const float*)d_in[5];
  const float* w_out     = (const float*)d_in[6];
  const float* b_out     = (const float*)d_in[7];
  float* out = (float*)d_out;
  char* ws = (char*)d_ws;

  ushort_t* xh      = (ushort_t*)(ws);                  // 16.78 MB
  ushort_t* xl      = (ushort_t*)(ws + 16777216);       // 16.78 MB
  ushort_t* qk_hi   = (ushort_t*)(ws + 33554432);       // 16.78 MB
  ushort_t* v_b     = (ushort_t*)(ws + 50331648);       // 16.78 MB
  float*    rot     = (float*)(ws + 67108864);          // 16.78 MB (dead after fallback)
  ushort_t* o_b     = (ushort_t*)(ws + 67108864);       // alias: lives after gather
  ushort_t* wqkTh   = (ushort_t*)(ws + 83886080);       // 512 KB
  ushort_t* wvT     = (ushort_t*)(ws + 84410368);       // 512 KB
  ushort_t* woT     = (ushort_t*)(ws + 84934656);       // 512 KB
  ushort_t* W2Th    = (ushort_t*)(ws + 85458944);       // 256 KB
  ushort_t* W2Tl    = (ushort_t*)(ws + 85721088);       // 256 KB
  float*    b2      = (float*)(ws + 85983232);          // 1 KB (pad to 4K)
  float*    scale   = (float*)(ws + 85987328);          // 64 KB
  int*      buckets = (int*)(ws + 86052864);            // 512 KB
  int*      st      = (int*)(ws + 86577152);            // 512 KB
  int*      mlist   = (int*)(ws + 87101440);            // 512 KB (cap 131072: can't overflow)
  int*      mcount  = (int*)(ws + 87625728);            // 4 KB
  ushort_t* so      = (ushort_t*)(ws + 87629824);       // g * 16.78 MB
  const size_t so_off = 87629824;

  int g = 1;
  for (int cand = 8; cand >= 1; cand >>= 1)
    if (so_off + (size_t)cand * 16777216ull <= ws_size) { g = cand; break; }

  const dim3 blk256(256);
  hipLaunchKernelGGL(split_x, dim3(4096), blk256, 0, stream, x, xh, xl, 1048576);
  hipLaunchKernelGGL(transpose_cvt, dim3(16, 16), blk256, 0, stream, w_qk, wqkTh);
  hipLaunchKernelGGL(transpose_cvt, dim3(16, 16), blk256, 0, stream, w_v, wvT);
  hipLaunchKernelGGL(transpose_cvt, dim3(16, 16), blk256, 0, stream, w_out, woT);
  hipLaunchKernelGGL(w2_split, dim3(513), blk256, 0, stream, w_qk, b_qk, rotations, W2Th, W2Tl, b2);

  hipLaunchKernelGGL(gemm_mfma_x2, dim3(128, 4), blk256, 0, stream, xh, xl, wqkTh, b_qk, qk_hi);
  hipLaunchKernelGGL(gemm_mfma, dim3(128, 4), blk256, 0, stream, xh, wvT, b_v, (float*)0, v_b, 1);
  hipLaunchKernelGGL(rot3_mfma, dim3(128, 2), blk256, 0, stream, xh, xl, W2Th, W2Tl, b2, rot);

  hipMemsetAsync(mcount, 0, 4, stream);
  hipLaunchKernelGGL(argmax_margin, dim3(16384), blk256, 0, stream, rot, buckets, mlist, mcount, 3e-3f);
  hipLaunchKernelGGL(bucket_fallback, dim3(256), dim3(512), 0, stream,
                     x, w_qk, b_qk, rotations, mlist, mcount, buckets);
  hipLaunchKernelGGL(sort_kernel, dim3(32), blk256, 0, stream, buckets, st);
  hipLaunchKernelGGL(scale_kernel, dim3(4096), blk256, 0, stream, qk_hi, scale);

  const int passes = 8 / g;
  for (int p = 0; p < passes; ++p) {
    const int hbase = p * g;
    hipLaunchKernelGGL(attn_mfma, dim3(4 * g * 64), blk256, 0, stream,
                       qk_hi, v_b, scale, st, so, g, hbase);
    hipLaunchKernelGGL(gather_kernel, dim3(16384), blk256, 0, stream,
                       so, o_b, g, (p == 0) ? 1 : 0);
  }

  hipLaunchKernelGGL(gemm_mfma, dim3(128, 4), blk256, 0, stream, o_b, woT, b_out, out, (ushort_t*)0, 0);
}